// Round 2
// baseline (1502.764 us; speedup 1.0000x reference)
//
#include <hip/hip_runtime.h>

#define N_NODES 8192
#define N_EDGES 32768
#define D_IN    1024
#define DH      256
#define NH      8
#define HD      2048   /* NH*DH */
#define NL      3
#define NT      5
#define NEG     0.2f
#define E2      (N_EDGES + N_NODES)

// ---------------------------------------------------------------- GEMM 64x64
// C[M,Nc] = A[M,K] @ B[K,Nc] + bias[Nc] (+ emb[types[m]][j] if emb != null)
// Requires M%64==0, Nc%64==0, K%16==0.
__global__ __launch_bounds__(256) void gemm64(
    const float* __restrict__ A, const float* __restrict__ B,
    const float* __restrict__ bias, float* __restrict__ C,
    int M, int K, int Nc,
    const float* __restrict__ emb, const int* __restrict__ types)
{
    __shared__ float as[16 * 64];   // transposed: as[k][row]
    __shared__ float bs[16 * 64];   // bs[k][col]
    const int tid = threadIdx.x;
    const int m0 = blockIdx.y * 64, n0 = blockIdx.x * 64;
    const int arow = tid >> 2, akq = (tid & 3) * 4;
    const int bkr = tid >> 4, bcq = (tid & 15) * 4;
    const int r0 = (tid >> 4) * 4, c0 = (tid & 15) * 4;
    float acc[4][4] = {};

    for (int kt = 0; kt < K; kt += 16) {
        float4 av = *(const float4*)(A + (size_t)(m0 + arow) * K + kt + akq);
        float4 bv = *(const float4*)(B + (size_t)(kt + bkr) * Nc + n0 + bcq);
        as[(akq + 0) * 64 + arow] = av.x;
        as[(akq + 1) * 64 + arow] = av.y;
        as[(akq + 2) * 64 + arow] = av.z;
        as[(akq + 3) * 64 + arow] = av.w;
        *(float4*)(bs + bkr * 64 + bcq) = bv;
        __syncthreads();
#pragma unroll
        for (int k = 0; k < 16; k++) {
            float a0 = as[k * 64 + r0 + 0], a1 = as[k * 64 + r0 + 1];
            float a2 = as[k * 64 + r0 + 2], a3 = as[k * 64 + r0 + 3];
            float b0 = bs[k * 64 + c0 + 0], b1 = bs[k * 64 + c0 + 1];
            float b2 = bs[k * 64 + c0 + 2], b3 = bs[k * 64 + c0 + 3];
            acc[0][0] += a0 * b0; acc[0][1] += a0 * b1; acc[0][2] += a0 * b2; acc[0][3] += a0 * b3;
            acc[1][0] += a1 * b0; acc[1][1] += a1 * b1; acc[1][2] += a1 * b2; acc[1][3] += a1 * b3;
            acc[2][0] += a2 * b0; acc[2][1] += a2 * b1; acc[2][2] += a2 * b2; acc[2][3] += a2 * b3;
            acc[3][0] += a3 * b0; acc[3][1] += a3 * b1; acc[3][2] += a3 * b2; acc[3][3] += a3 * b3;
        }
        __syncthreads();
    }
#pragma unroll
    for (int i = 0; i < 4; i++) {
        int row = m0 + r0 + i;
        float embv[4] = {0.f, 0.f, 0.f, 0.f};
        if (emb) {
            int t = types[row];
#pragma unroll
            for (int j = 0; j < 4; j++) embv[j] = emb[t * DH + n0 + c0 + j];
        }
#pragma unroll
        for (int j = 0; j < 4; j++) {
            float v = acc[i][j] + bias[n0 + c0 + j] + embv[j];
            C[(size_t)row * Nc + n0 + c0 + j] = v;
        }
    }
}

// ------------------------------------------------------- E5 = edge_emb @ We
__global__ __launch_bounds__(256) void e5_kernel(
    const float* __restrict__ eemb, const float* __restrict__ We,
    float* __restrict__ E5)
{
    int col = blockIdx.x * 256 + threadIdx.x;  // 0..HD-1
    int t = blockIdx.y;                        // 0..NT-1
    float acc = 0.f;
    for (int k = 0; k < DH; k++) acc += eemb[t * DH + k] * We[(size_t)k * HD + col];
    E5[(size_t)t * HD + col] = acc;
}

// ------------------------------------------------------- degree + attr hist
__global__ void deg_hist(const int* __restrict__ dst, const int* __restrict__ attr,
                         int* cnt, int* hist)
{
    int e = blockIdx.x * 256 + threadIdx.x;
    if (e < N_EDGES) {
        int d = dst[e];
        atomicAdd(&cnt[d], 1);
        atomicAdd(&hist[d * NT + attr[e]], 1);
    }
}

// ----------------------------------------------------------- rowptr scan
__global__ __launch_bounds__(256) void scan_kernel(const int* __restrict__ cnt,
                                                   int* __restrict__ rowptr)
{
    __shared__ int part[256];
    int tid = threadIdx.x;
    int base = tid * 32, s = 0;
    for (int i = 0; i < 32; i++) s += cnt[base + i];
    part[tid] = s;
    __syncthreads();
    for (int off = 1; off < 256; off <<= 1) {
        int v = (tid >= off) ? part[tid - off] : 0;
        __syncthreads();
        part[tid] += v;
        __syncthreads();
    }
    int run = (tid == 0) ? 0 : part[tid - 1];
    for (int i = 0; i < 32; i++) { rowptr[base + i] = run; run += cnt[base + i]; }
    if (tid == 255) rowptr[N_NODES] = run;
}

// ----------------------------------------------------------- CSR fill
__global__ void csr_fill(const int* __restrict__ dst, const int* __restrict__ rowptr,
                         int* fillc, int* __restrict__ csr)
{
    int e = blockIdx.x * 256 + threadIdx.x;
    if (e < N_EDGES) {
        int d = dst[e];
        int p = atomicAdd(&fillc[d], 1);
        csr[rowptr[d] + p] = e;
    }
}

// ----------------------------------------------------------- logits per edge
// logits[e,h] = sum_c lrelu(xl[s,h,c] + xr[d,h,c] + ee[e,h,c]) * att[h,c]
__global__ __launch_bounds__(256) void logits_kernel(
    const float* __restrict__ xl, const float* __restrict__ xr,
    const float* __restrict__ E5, const float* __restrict__ att,
    const int* __restrict__ src, const int* __restrict__ dst,
    const int* __restrict__ attr, const int* __restrict__ cnt,
    const int* __restrict__ hist, float* __restrict__ logits)
{
    __shared__ float part[4][8];
    const int e = blockIdx.x;
    const int tid = threadIdx.x, lane = tid & 63, w = tid >> 6;
    int s, d, a = 0;
    float wt[NT];
    const bool isloop = (e >= N_EDGES);
    if (isloop) {
        int n = e - N_EDGES;
        s = n; d = n;
        float inv = 1.f / fmaxf((float)cnt[n], 1.f);
#pragma unroll
        for (int t = 0; t < NT; t++) wt[t] = inv * (float)hist[n * NT + t];
    } else {
        s = src[e]; d = dst[e]; a = attr[e];
    }
    const float* xls = xl + (size_t)s * HD;
    const float* xrd = xr + (size_t)d * HD;
#pragma unroll 1
    for (int h = 0; h < NH; h++) {
        int c = h * DH + tid;
        float ee;
        if (isloop) {
            ee = 0.f;
#pragma unroll
            for (int t = 0; t < NT; t++) ee += wt[t] * E5[(size_t)t * HD + c];
        } else {
            ee = E5[(size_t)a * HD + c];
        }
        float z = xls[c] + xrd[c] + ee;
        z = (z >= 0.f) ? z : NEG * z;
        float v = z * att[h * DH + tid];
        for (int off = 32; off; off >>= 1) v += __shfl_down(v, off, 64);
        if (lane == 0) part[w][h] = v;
    }
    __syncthreads();
    if (tid < NH)
        logits[(size_t)e * NH + tid] =
            part[0][tid] + part[1][tid] + part[2][tid] + part[3][tid];
}

// --------------------------- per-node: softmax + aggregate + mean + bias + relu
__global__ __launch_bounds__(256) void node_kernel(
    const float* __restrict__ xl, const float* __restrict__ logits,
    const int* __restrict__ csr, const int* __restrict__ rowptr,
    const int* __restrict__ cnt, const int* __restrict__ src,
    const float* __restrict__ bgat, float* __restrict__ hout)
{
    const int n = blockIdx.x, tid = threadIdx.x;
    __shared__ float lmax[8], denom[8];
    __shared__ float alph[32][8];
    __shared__ float outs[8][256];
    const int deg = cnt[n];
    const int m = deg + 1;               // + self loop
    const int r0 = rowptr[n];

    if (tid < NH) {
        float mx = -1e30f;
        for (int i = 0; i < m; i++) {
            int eid = (i < deg) ? csr[r0 + i] : (N_EDGES + n);
            mx = fmaxf(mx, logits[(size_t)eid * NH + tid]);
        }
        float sm = 0.f;
        for (int i = 0; i < m; i++) {
            int eid = (i < deg) ? csr[r0 + i] : (N_EDGES + n);
            sm += expf(logits[(size_t)eid * NH + tid] - mx);
        }
        lmax[tid] = mx;
        denom[tid] = sm;
    }
    __syncthreads();

    const int h = tid >> 5, cb = tid & 31;
    float acc[8] = {0.f, 0.f, 0.f, 0.f, 0.f, 0.f, 0.f, 0.f};
    for (int i0 = 0; i0 < m; i0 += 32) {
        int chunk = min(32, m - i0);
        if (tid < chunk * 8) {
            int ci = tid >> 3, hh = tid & 7;
            int i = i0 + ci;
            int eid = (i < deg) ? csr[r0 + i] : (N_EDGES + n);
            alph[ci][hh] = expf(logits[(size_t)eid * NH + hh] - lmax[hh]) / denom[hh];
        }
        __syncthreads();
        for (int ci = 0; ci < chunk; ci++) {
            int i = i0 + ci;
            int eid = (i < deg) ? csr[r0 + i] : (N_EDGES + n);
            int s = (eid < N_EDGES) ? src[eid] : n;
            float al = alph[ci][h];
            const float* xp = xl + (size_t)s * HD + h * DH + cb * 8;
            float4 v0 = *(const float4*)xp;
            float4 v1 = *(const float4*)(xp + 4);
            acc[0] += al * v0.x; acc[1] += al * v0.y;
            acc[2] += al * v0.z; acc[3] += al * v0.w;
            acc[4] += al * v1.x; acc[5] += al * v1.y;
            acc[6] += al * v1.z; acc[7] += al * v1.w;
        }
        __syncthreads();
    }
#pragma unroll
    for (int j = 0; j < 8; j++) outs[h][cb * 8 + j] = acc[j];
    __syncthreads();
    float o = 0.f;
#pragma unroll
    for (int hh = 0; hh < NH; hh++) o += outs[hh][tid];
    o = o * 0.125f + bgat[tid];
    hout[(size_t)n * DH + tid] = fmaxf(o, 0.f);
}

// ---------------------------------------------------------------------------
extern "C" void kernel_launch(void* const* d_in, const int* in_sizes, int n_in,
                              void* d_out, int out_size, void* d_ws, size_t ws_size,
                              hipStream_t stream)
{
    const float* x     = (const float*)d_in[0];
    const int*   eidx  = (const int*)d_in[1];
    const int*   src   = eidx;
    const int*   dst   = eidx + N_EDGES;
    const int*   attr  = (const int*)d_in[2];
    const int*   types = (const int*)d_in[3];
    const float* W_in  = (const float*)d_in[4];
    const float* b_in  = (const float*)d_in[5];
    const float* nemb  = (const float*)d_in[6];
    const float* eemb  = (const float*)d_in[7];
    const float* Wl    = (const float*)d_in[8];
    const float* bl    = (const float*)d_in[9];
    const float* Wr    = (const float*)d_in[10];
    const float* br    = (const float*)d_in[11];
    const float* We    = (const float*)d_in[12];
    const float* att   = (const float*)d_in[13];
    const float* bgat  = (const float*)d_in[14];
    const float* W_out = (const float*)d_in[15];
    const float* b_out = (const float*)d_in[16];
    float* out = (float*)d_out;

    char* ws = (char*)d_ws;
    size_t off = 0;
    auto alloc = [&](size_t bytes) -> void* {
        void* p = ws + off;
        off += (bytes + 255) & ~(size_t)255;
        return p;
    };
    float* h      = (float*)alloc((size_t)N_NODES * DH * 4);
    float* xl     = (float*)alloc((size_t)N_NODES * HD * 4);
    float* xr     = (float*)alloc((size_t)N_NODES * HD * 4);
    float* logits = (float*)alloc((size_t)E2 * NH * 4);
    float* E5     = (float*)alloc((size_t)NT * HD * 4);
    int* cnt      = (int*)alloc((size_t)N_NODES * 4);
    int* hist     = (int*)alloc((size_t)N_NODES * NT * 4);
    int* rowptr   = (int*)alloc((size_t)(N_NODES + 1) * 4);
    int* fillc    = (int*)alloc((size_t)N_NODES * 4);
    int* csr      = (int*)alloc((size_t)N_EDGES * 4);

    hipMemsetAsync(cnt, 0, (size_t)N_NODES * 4, stream);
    hipMemsetAsync(hist, 0, (size_t)N_NODES * NT * 4, stream);
    hipMemsetAsync(fillc, 0, (size_t)N_NODES * 4, stream);

    deg_hist<<<(N_EDGES + 255) / 256, 256, 0, stream>>>(dst, attr, cnt, hist);
    scan_kernel<<<1, 256, 0, stream>>>(cnt, rowptr);
    csr_fill<<<(N_EDGES + 255) / 256, 256, 0, stream>>>(dst, rowptr, fillc, csr);

    // h = x @ W_in + b_in + node_emb[types]
    gemm64<<<dim3(DH / 64, N_NODES / 64), 256, 0, stream>>>(
        x, W_in, b_in, h, N_NODES, D_IN, DH, nemb, types);

    for (int l = 0; l < NL; l++) {
        const float* Wl_l = Wl + (size_t)l * DH * HD;
        const float* Wr_l = Wr + (size_t)l * DH * HD;
        const float* We_l = We + (size_t)l * DH * HD;
        gemm64<<<dim3(HD / 64, N_NODES / 64), 256, 0, stream>>>(
            h, Wl_l, bl + (size_t)l * HD, xl, N_NODES, DH, HD, nullptr, nullptr);
        gemm64<<<dim3(HD / 64, N_NODES / 64), 256, 0, stream>>>(
            h, Wr_l, br + (size_t)l * HD, xr, N_NODES, DH, HD, nullptr, nullptr);
        e5_kernel<<<dim3(HD / 256, NT), 256, 0, stream>>>(eemb, We_l, E5);
        logits_kernel<<<E2, 256, 0, stream>>>(
            xl, xr, E5, att + (size_t)l * NH * DH, src, dst, attr, cnt, hist, logits);
        node_kernel<<<N_NODES, 256, 0, stream>>>(
            xl, logits, csr, rowptr, cnt, src, bgat + (size_t)l * DH, h);
    }

    // out = h @ W_out + b_out
    gemm64<<<dim3(DH / 64, N_NODES / 64), 256, 0, stream>>>(
        h, W_out, b_out, out, N_NODES, DH, DH, nullptr, nullptr);
}

// Round 4
// 1443.875 us; speedup vs baseline: 1.0408x; 1.0408x over previous
//
#include <hip/hip_runtime.h>

#define N_NODES 8192
#define N_EDGES 32768
#define D_IN    1024
#define DH      256
#define NH      8
#define HD      2048   /* NH*DH */
#define NL      3
#define NT      5
#define NEG     0.2f
#define E2      (N_EDGES + N_NODES)
#define CAP     64      /* per-node LDS logit capacity (deg+1 beyond -> global spill) */

// ---------------------------------------------------------------- GEMM 64x64
// C[M,Nc] = A[M,K] @ B[K,Nc] + bias[Nc] (+ emb[types[m]][j] if emb != null)
__global__ __launch_bounds__(256) void gemm64(
    const float* __restrict__ A, const float* __restrict__ B,
    const float* __restrict__ bias, float* __restrict__ C,
    int M, int K, int Nc,
    const float* __restrict__ emb, const int* __restrict__ types)
{
    __shared__ float as[16 * 64];   // transposed: as[k][row]
    __shared__ float bs[16 * 64];   // bs[k][col]
    const int tid = threadIdx.x;
    const int m0 = blockIdx.y * 64, n0 = blockIdx.x * 64;
    const int arow = tid >> 2, akq = (tid & 3) * 4;
    const int bkr = tid >> 4, bcq = (tid & 15) * 4;
    const int r0 = (tid >> 4) * 4, c0 = (tid & 15) * 4;
    float acc[4][4] = {};

    for (int kt = 0; kt < K; kt += 16) {
        float4 av = *(const float4*)(A + (size_t)(m0 + arow) * K + kt + akq);
        float4 bv = *(const float4*)(B + (size_t)(kt + bkr) * Nc + n0 + bcq);
        as[(akq + 0) * 64 + arow] = av.x;
        as[(akq + 1) * 64 + arow] = av.y;
        as[(akq + 2) * 64 + arow] = av.z;
        as[(akq + 3) * 64 + arow] = av.w;
        *(float4*)(bs + bkr * 64 + bcq) = bv;
        __syncthreads();
#pragma unroll
        for (int k = 0; k < 16; k++) {
            float a0 = as[k * 64 + r0 + 0], a1 = as[k * 64 + r0 + 1];
            float a2 = as[k * 64 + r0 + 2], a3 = as[k * 64 + r0 + 3];
            float b0 = bs[k * 64 + c0 + 0], b1 = bs[k * 64 + c0 + 1];
            float b2 = bs[k * 64 + c0 + 2], b3 = bs[k * 64 + c0 + 3];
            acc[0][0] += a0 * b0; acc[0][1] += a0 * b1; acc[0][2] += a0 * b2; acc[0][3] += a0 * b3;
            acc[1][0] += a1 * b0; acc[1][1] += a1 * b1; acc[1][2] += a1 * b2; acc[1][3] += a1 * b3;
            acc[2][0] += a2 * b0; acc[2][1] += a2 * b1; acc[2][2] += a2 * b2; acc[2][3] += a2 * b3;
            acc[3][0] += a3 * b0; acc[3][1] += a3 * b1; acc[3][2] += a3 * b2; acc[3][3] += a3 * b3;
        }
        __syncthreads();
    }
#pragma unroll
    for (int i = 0; i < 4; i++) {
        int row = m0 + r0 + i;
        float embv[4] = {0.f, 0.f, 0.f, 0.f};
        if (emb) {
            int t = types[row];
#pragma unroll
            for (int j = 0; j < 4; j++) embv[j] = emb[t * DH + n0 + c0 + j];
        }
#pragma unroll
        for (int j = 0; j < 4; j++) {
            float v = acc[i][j] + bias[n0 + c0 + j] + embv[j];
            C[(size_t)row * Nc + n0 + c0 + j] = v;
        }
    }
}

// ------------------------------------------------------- E5 = edge_emb @ We
__global__ __launch_bounds__(256) void e5_kernel(
    const float* __restrict__ eemb, const float* __restrict__ We,
    float* __restrict__ E5)
{
    int col = blockIdx.x * 256 + threadIdx.x;  // 0..HD-1
    int t = blockIdx.y;                        // 0..NT-1
    float acc = 0.f;
    for (int k = 0; k < DH; k++) acc += eemb[t * DH + k] * We[(size_t)k * HD + col];
    E5[(size_t)t * HD + col] = acc;
}

// ------------------------------------------------------- degree + attr hist
__global__ void deg_hist(const int* __restrict__ dst, const int* __restrict__ attr,
                         int* cnt, int* hist)
{
    int e = blockIdx.x * 256 + threadIdx.x;
    if (e < N_EDGES) {
        int d = dst[e];
        atomicAdd(&cnt[d], 1);
        atomicAdd(&hist[d * NT + attr[e]], 1);
    }
}

// ----------------------------------------------------------- rowptr scan
__global__ __launch_bounds__(256) void scan_kernel(const int* __restrict__ cnt,
                                                   int* __restrict__ rowptr)
{
    __shared__ int part[256];
    int tid = threadIdx.x;
    int base = tid * 32, s = 0;
    for (int i = 0; i < 32; i++) s += cnt[base + i];
    part[tid] = s;
    __syncthreads();
    for (int off = 1; off < 256; off <<= 1) {
        int v = (tid >= off) ? part[tid - off] : 0;
        __syncthreads();
        part[tid] += v;
        __syncthreads();
    }
    int run = (tid == 0) ? 0 : part[tid - 1];
    for (int i = 0; i < 32; i++) { rowptr[base + i] = run; run += cnt[base + i]; }
    if (tid == 255) rowptr[N_NODES] = run;
}

// ----------------------------------------------------------- CSR fill
__global__ void csr_fill(const int* __restrict__ dst, const int* __restrict__ rowptr,
                         int* fillc, int* __restrict__ csr)
{
    int e = blockIdx.x * 256 + threadIdx.x;
    if (e < N_EDGES) {
        int d = dst[e];
        int p = atomicAdd(&fillc[d], 1);
        csr[rowptr[d] + p] = e;
    }
}

// ---------------- fused per-node: logits + softmax + aggregate + mean + relu
// One block per destination node n. Edges from CSR + implicit self loop.
__global__ __launch_bounds__(256) void gat_fused(
    const float* __restrict__ xl, const float* __restrict__ xr,
    const float* __restrict__ E5, const float* __restrict__ att,
    const int* __restrict__ csr, const int* __restrict__ rowptr,
    const int* __restrict__ cnt, const int* __restrict__ src,
    const int* __restrict__ attr, const int* __restrict__ hist,
    const float* __restrict__ bgat, float* __restrict__ glog,
    float* __restrict__ hout)
{
    const int n = blockIdx.x, tid = threadIdx.x;
    const int lane = tid & 63, w = tid >> 6;
    __shared__ float xrs[HD];          // xr[n] row, 8 KB
    __shared__ float part[4][8];
    __shared__ float lg[CAP][8];       // logits -> alpha
    __shared__ int   ssrc[CAP];        // src node per entry
    __shared__ float lmax[8], denom[8];
    __shared__ float outs[8][256];

    const int deg = cnt[n];
    const int m = deg + 1;             // + self loop
    const int r0 = rowptr[n];

    // self-loop edge_attr weights (fill_value='mean')
    float wt[NT];
    {
        float inv = 1.f / fmaxf((float)deg, 1.f);
#pragma unroll
        for (int t = 0; t < NT; t++) wt[t] = inv * (float)hist[n * NT + t];
    }
    // cache att row slice in registers: attv[h] = att[h*DH + tid]
    float attv[NH];
#pragma unroll
    for (int h = 0; h < NH; h++) attv[h] = att[h * DH + tid];
    // load xr row into LDS
#pragma unroll
    for (int c = tid; c < HD; c += 256) xrs[c] = xr[(size_t)n * HD + c];
    __syncthreads();

    // ---- phase A: logits per edge ----
    for (int i = 0; i < m; i++) {
        const bool isloop = (i == deg);
        int s, a = 0;
        if (isloop) { s = n; }
        else { int e = csr[r0 + i]; s = src[e]; a = attr[e]; }
        if (tid == 0 && i < CAP) ssrc[i] = s;
        const float* xlp = xl + (size_t)s * HD;
        float contrib[NH];
#pragma unroll
        for (int h = 0; h < NH; h++) {
            int c = h * DH + tid;
            float ee;
            if (isloop) {
                ee = wt[0] * E5[c] + wt[1] * E5[HD + c] + wt[2] * E5[2 * HD + c]
                   + wt[3] * E5[3 * HD + c] + wt[4] * E5[4 * HD + c];
            } else {
                ee = E5[(size_t)a * HD + c];
            }
            float z = xlp[c] + xrs[c] + ee;
            z = (z >= 0.f) ? z : NEG * z;
            contrib[h] = z * attv[h];
        }
#pragma unroll
        for (int h = 0; h < NH; h++) {
            float v = contrib[h];
            for (int off = 32; off; off >>= 1) v += __shfl_down(v, off, 64);
            if (lane == 0) part[w][h] = v;
        }
        __syncthreads();
        if (tid < NH) {
            float l = part[0][tid] + part[1][tid] + part[2][tid] + part[3][tid];
            if (i < CAP) lg[i][tid] = l;
            else {
                int eid = isloop ? (N_EDGES + n) : csr[r0 + i];
                glog[(size_t)eid * NH + tid] = l;
            }
        }
        __syncthreads();   // part reused next iteration
    }

    // ---- softmax stats ----
    if (tid < NH) {
        float mx = -1e30f;
        for (int i = 0; i < m; i++) {
            float l;
            if (i < CAP) l = lg[i][tid];
            else {
                int eid = (i < deg) ? csr[r0 + i] : (N_EDGES + n);
                l = glog[(size_t)eid * NH + tid];
            }
            mx = fmaxf(mx, l);
        }
        float sm = 0.f;
        for (int i = 0; i < m; i++) {
            float l;
            if (i < CAP) l = lg[i][tid];
            else {
                int eid = (i < deg) ? csr[r0 + i] : (N_EDGES + n);
                l = glog[(size_t)eid * NH + tid];
            }
            sm += expf(l - mx);
        }
        lmax[tid] = mx;
        denom[tid] = sm;
    }
    __syncthreads();

    // ---- alpha in place ----
    for (int idx = tid; idx < m * NH; idx += 256) {
        int i = idx >> 3, hh = idx & 7;
        if (i < CAP) {
            lg[i][hh] = expf(lg[i][hh] - lmax[hh]) / denom[hh];
        } else {
            int eid = (i < deg) ? csr[r0 + i] : (N_EDGES + n);
            size_t p = (size_t)eid * NH + hh;
            glog[p] = expf(glog[p] - lmax[hh]) / denom[hh];
        }
    }
    __syncthreads();

    // ---- phase B: weighted aggregation (xl rows are cache-hot from phase A) ----
    const int h = tid >> 5, cb = tid & 31;
    float acc[8] = {0.f, 0.f, 0.f, 0.f, 0.f, 0.f, 0.f, 0.f};
    for (int i = 0; i < m; i++) {
        int s;
        float al;
        if (i < CAP) { s = ssrc[i]; al = lg[i][h]; }
        else {
            int eid = (i < deg) ? csr[r0 + i] : (N_EDGES + n);
            s = (i < deg) ? src[eid] : n;
            al = glog[(size_t)eid * NH + h];
        }
        const float* xp = xl + (size_t)s * HD + h * DH + cb * 8;
        float4 v0 = *(const float4*)xp;
        float4 v1 = *(const float4*)(xp + 4);
        acc[0] += al * v0.x; acc[1] += al * v0.y;
        acc[2] += al * v0.z; acc[3] += al * v0.w;
        acc[4] += al * v1.x; acc[5] += al * v1.y;
        acc[6] += al * v1.z; acc[7] += al * v1.w;
    }
#pragma unroll
    for (int j = 0; j < 8; j++) outs[h][cb * 8 + j] = acc[j];
    __syncthreads();
    float o = 0.f;
#pragma unroll
    for (int hh = 0; hh < NH; hh++) o += outs[hh][tid];
    o = o * 0.125f + bgat[tid];
    hout[(size_t)n * DH + tid] = fmaxf(o, 0.f);
}

// ---------------------------------------------------------------------------
extern "C" void kernel_launch(void* const* d_in, const int* in_sizes, int n_in,
                              void* d_out, int out_size, void* d_ws, size_t ws_size,
                              hipStream_t stream)
{
    const float* x     = (const float*)d_in[0];
    const int*   eidx  = (const int*)d_in[1];
    const int*   src   = eidx;
    const int*   dst   = eidx + N_EDGES;
    const int*   attr  = (const int*)d_in[2];
    const int*   types = (const int*)d_in[3];
    const float* W_in  = (const float*)d_in[4];
    const float* b_in  = (const float*)d_in[5];
    const float* nemb  = (const float*)d_in[6];
    const float* eemb  = (const float*)d_in[7];
    const float* Wl    = (const float*)d_in[8];
    const float* bl    = (const float*)d_in[9];
    const float* Wr    = (const float*)d_in[10];
    const float* br    = (const float*)d_in[11];
    const float* We    = (const float*)d_in[12];
    const float* att   = (const float*)d_in[13];
    const float* bgat  = (const float*)d_in[14];
    const float* W_out = (const float*)d_in[15];
    const float* b_out = (const float*)d_in[16];
    float* out = (float*)d_out;

    char* ws = (char*)d_ws;
    size_t off = 0;
    auto alloc = [&](size_t bytes) -> void* {
        void* p = ws + off;
        off += (bytes + 255) & ~(size_t)255;
        return p;
    };
    float* h      = (float*)alloc((size_t)N_NODES * DH * 4);
    float* xl     = (float*)alloc((size_t)N_NODES * HD * 4);
    float* xr     = (float*)alloc((size_t)N_NODES * HD * 4);
    float* glog   = (float*)alloc((size_t)E2 * NH * 4);
    float* E5     = (float*)alloc((size_t)NT * HD * 4);
    int* cnt      = (int*)alloc((size_t)N_NODES * 4);
    int* hist     = (int*)alloc((size_t)N_NODES * NT * 4);
    int* rowptr   = (int*)alloc((size_t)(N_NODES + 1) * 4);
    int* fillc    = (int*)alloc((size_t)N_NODES * 4);
    int* csr      = (int*)alloc((size_t)N_EDGES * 4);

    hipMemsetAsync(cnt, 0, (size_t)N_NODES * 4, stream);
    hipMemsetAsync(hist, 0, (size_t)N_NODES * NT * 4, stream);
    hipMemsetAsync(fillc, 0, (size_t)N_NODES * 4, stream);

    deg_hist<<<(N_EDGES + 255) / 256, 256, 0, stream>>>(dst, attr, cnt, hist);
    scan_kernel<<<1, 256, 0, stream>>>(cnt, rowptr);
    csr_fill<<<(N_EDGES + 255) / 256, 256, 0, stream>>>(dst, rowptr, fillc, csr);

    // h = x @ W_in + b_in + node_emb[types]
    gemm64<<<dim3(DH / 64, N_NODES / 64), 256, 0, stream>>>(
        x, W_in, b_in, h, N_NODES, D_IN, DH, nemb, types);

    for (int l = 0; l < NL; l++) {
        const float* Wl_l = Wl + (size_t)l * DH * HD;
        const float* Wr_l = Wr + (size_t)l * DH * HD;
        const float* We_l = We + (size_t)l * DH * HD;
        gemm64<<<dim3(HD / 64, N_NODES / 64), 256, 0, stream>>>(
            h, Wl_l, bl + (size_t)l * HD, xl, N_NODES, DH, HD, nullptr, nullptr);
        gemm64<<<dim3(HD / 64, N_NODES / 64), 256, 0, stream>>>(
            h, Wr_l, br + (size_t)l * HD, xr, N_NODES, DH, HD, nullptr, nullptr);
        e5_kernel<<<dim3(HD / 256, NT), 256, 0, stream>>>(eemb, We_l, E5);
        gat_fused<<<N_NODES, 256, 0, stream>>>(
            xl, xr, E5, att + (size_t)l * NH * DH, csr, rowptr, cnt, src, attr,
            hist, bgat + (size_t)l * DH, glog, h);
    }

    // out = h @ W_out + b_out
    gemm64<<<dim3(DH / 64, N_NODES / 64), 256, 0, stream>>>(
        h, W_out, b_out, out, N_NODES, DH, DH, nullptr, nullptr);
}

// Round 5
// 1168.775 us; speedup vs baseline: 1.2858x; 1.2354x over previous
//
#include <hip/hip_runtime.h>

#define N_NODES 8192
#define N_EDGES 32768
#define D_IN    1024
#define DH      256
#define NH      8
#define HD      2048   /* NH*DH */
#define NL      3
#define NT      5
#define NEG     0.2f
#define E2      (N_EDGES + N_NODES)
#define CAP     64
#define PADK    40     /* LDS row stride in bf16 elems (80 B -> 2-way bank alias, free) */

typedef __bf16 bf16x8 __attribute__((ext_vector_type(8)));
typedef float  f32x4  __attribute__((ext_vector_type(4)));
typedef unsigned short ushort8 __attribute__((ext_vector_type(8)));

static __device__ __forceinline__ unsigned short f2bf(float f) {
    unsigned u = __float_as_uint(f);
    unsigned r = (u + 0x7FFFu + ((u >> 16) & 1u)) >> 16;
    return (unsigned short)r;
}
static __device__ __forceinline__ float bf2f(unsigned short h) {
    return __uint_as_float(((unsigned)h) << 16);
}

// -------------------------------------------------- activation split (hi|hi|lo)
// X fp32 [M,K] -> A3 bf16 [M, 3K];  K = 1<<kshift
__global__ __launch_bounds__(256) void split_act(
    const float* __restrict__ X, unsigned short* __restrict__ A3,
    int MK, int kshift)
{
    int idx = blockIdx.x * 256 + threadIdx.x;
    if (idx >= MK) return;
    int K = 1 << kshift;
    int m = idx >> kshift, k = idx & (K - 1);
    float v = X[idx];
    unsigned short hu = f2bf(v);
    unsigned short lu = f2bf(v - bf2f(hu));
    size_t b = (size_t)m * 3 * K + k;
    A3[b]         = hu;
    A3[b + K]     = hu;
    A3[b + 2 * K] = lu;
}

// -------------------------------------------- weight split+transpose (hi;lo;hi)
// W fp32 [K,N] -> B3T bf16 [N, 3K]:  B3T[n][k]=hi, [n][K+k]=lo, [n][2K+k]=hi
__global__ __launch_bounds__(256) void split_w(
    const float* __restrict__ W, unsigned short* __restrict__ B3T,
    int K, int N)
{
    __shared__ float t[32][33];
    int k0 = blockIdx.y * 32, n0 = blockIdx.x * 32;
    int tid = threadIdx.x;
    int r = tid >> 5, c = tid & 31;
    for (int rr = r; rr < 32; rr += 8)
        t[rr][c] = W[(size_t)(k0 + rr) * N + n0 + c];
    __syncthreads();
    for (int rr = r; rr < 32; rr += 8) {
        int n = n0 + rr, k = k0 + c;
        float v = t[c][rr];
        unsigned short hu = f2bf(v);
        unsigned short lu = f2bf(v - bf2f(hu));
        size_t b = (size_t)n * 3 * K + k;
        B3T[b]         = hu;
        B3T[b + K]     = lu;
        B3T[b + 2 * K] = hu;
    }
}

// --------------------------------------------------------- MFMA GEMM 128x128
// C[M,N] = A3[M,K3] * B3T[N,K3]^T + bias[N] (+ emb[types[m]][n] if emb)
// M%128==0, N%128==0, K3%32==0.
__global__ __launch_bounds__(256) void gemm_mfma(
    const unsigned short* __restrict__ A3, const unsigned short* __restrict__ B3T,
    const float* __restrict__ bias, float* __restrict__ C,
    int M, int N, int K3,
    const float* __restrict__ emb, const int* __restrict__ types)
{
    __shared__ unsigned short aLds[128 * PADK];
    __shared__ unsigned short bLds[128 * PADK];
    const int tid = threadIdx.x;
    const int m0 = blockIdx.y * 128, n0 = blockIdx.x * 128;
    const int lane = tid & 63, wid = tid >> 6;
    const int wm = wid >> 1, wn = wid & 1;          // 2x2 waves, 64x64 each
    const int srow = tid >> 2, scq = (tid & 3) * 8; // staging: 4 x 8 elems per row
    const int frow = lane & 15, fkq = (lane >> 4) * 8;

    f32x4 acc[4][4] = {};

    for (int kt = 0; kt < K3; kt += 32) {
        // stage A,B tiles (128x32 bf16 each), 2 rounds of 256 thr x 16 B
#pragma unroll
        for (int rnd = 0; rnd < 2; rnd++) {
            int row = rnd * 64 + srow;
            ushort8 av = *(const ushort8*)(A3 + (size_t)(m0 + row) * K3 + kt + scq);
            ushort8 bv = *(const ushort8*)(B3T + (size_t)(n0 + row) * K3 + kt + scq);
            *(ushort8*)(aLds + row * PADK + scq) = av;
            *(ushort8*)(bLds + row * PADK + scq) = bv;
        }
        __syncthreads();
        bf16x8 af[4], bf[4];
#pragma unroll
        for (int f = 0; f < 4; f++) {
            af[f] = *(const bf16x8*)(aLds + (wm * 64 + f * 16 + frow) * PADK + fkq);
            bf[f] = *(const bf16x8*)(bLds + (wn * 64 + f * 16 + frow) * PADK + fkq);
        }
#pragma unroll
        for (int i = 0; i < 4; i++)
#pragma unroll
            for (int j = 0; j < 4; j++)
                acc[i][j] = __builtin_amdgcn_mfma_f32_16x16x32_bf16(
                    af[i], bf[j], acc[i][j], 0, 0, 0);
        __syncthreads();
    }

    // epilogue: C frag layout col=lane&15, row=(lane>>4)*4+r
    const int ccol = lane & 15, crq = (lane >> 4) * 4;
#pragma unroll
    for (int j = 0; j < 4; j++) {
        int gcol = n0 + wn * 64 + j * 16 + ccol;
        float bv = bias[gcol];
#pragma unroll
        for (int i = 0; i < 4; i++) {
#pragma unroll
            for (int r = 0; r < 4; r++) {
                int grow = m0 + wm * 64 + i * 16 + crq + r;
                float v = acc[i][j][r] + bv;
                if (emb) v += emb[types[grow] * DH + gcol];
                C[(size_t)grow * N + gcol] = v;
            }
        }
    }
}

// ------------------------------------------------------- E5 = edge_emb @ We
__global__ __launch_bounds__(256) void e5_kernel(
    const float* __restrict__ eemb, const float* __restrict__ We,
    float* __restrict__ E5)
{
    int col = blockIdx.x * 256 + threadIdx.x;
    int t = blockIdx.y;
    float acc = 0.f;
    for (int k = 0; k < DH; k++) acc += eemb[t * DH + k] * We[(size_t)k * HD + col];
    E5[(size_t)t * HD + col] = acc;
}

// ------------------------------------------------------- degree + attr hist
__global__ void deg_hist(const int* __restrict__ dst, const int* __restrict__ attr,
                         int* cnt, int* hist)
{
    int e = blockIdx.x * 256 + threadIdx.x;
    if (e < N_EDGES) {
        int d = dst[e];
        atomicAdd(&cnt[d], 1);
        atomicAdd(&hist[d * NT + attr[e]], 1);
    }
}

// ----------------------------------------------------------- rowptr scan
__global__ __launch_bounds__(256) void scan_kernel(const int* __restrict__ cnt,
                                                   int* __restrict__ rowptr)
{
    __shared__ int part[256];
    int tid = threadIdx.x;
    int base = tid * 32, s = 0;
    for (int i = 0; i < 32; i++) s += cnt[base + i];
    part[tid] = s;
    __syncthreads();
    for (int off = 1; off < 256; off <<= 1) {
        int v = (tid >= off) ? part[tid - off] : 0;
        __syncthreads();
        part[tid] += v;
        __syncthreads();
    }
    int run = (tid == 0) ? 0 : part[tid - 1];
    for (int i = 0; i < 32; i++) { rowptr[base + i] = run; run += cnt[base + i]; }
    if (tid == 255) rowptr[N_NODES] = run;
}

// ----------------------------------------------------------- CSR fill
__global__ void csr_fill(const int* __restrict__ dst, const int* __restrict__ rowptr,
                         int* fillc, int* __restrict__ csr)
{
    int e = blockIdx.x * 256 + threadIdx.x;
    if (e < N_EDGES) {
        int d = dst[e];
        int p = atomicAdd(&fillc[d], 1);
        csr[rowptr[d] + p] = e;
    }
}

// ---------------- fused per-node: logits + softmax + aggregate + mean + relu
__global__ __launch_bounds__(256) void gat_fused(
    const float* __restrict__ xl, const float* __restrict__ xr,
    const float* __restrict__ E5, const float* __restrict__ att,
    const int* __restrict__ csr, const int* __restrict__ rowptr,
    const int* __restrict__ cnt, const int* __restrict__ src,
    const int* __restrict__ attr, const int* __restrict__ hist,
    const float* __restrict__ bgat, float* __restrict__ glog,
    float* __restrict__ hout)
{
    const int n = blockIdx.x, tid = threadIdx.x;
    const int lane = tid & 63, w = tid >> 6;
    __shared__ float xrs[HD];
    __shared__ float part[4][8];
    __shared__ float lg[CAP][8];
    __shared__ int   ssrc[CAP];
    __shared__ float lmax[8], denom[8];
    __shared__ float outs[8][256];

    const int deg = cnt[n];
    const int m = deg + 1;
    const int r0 = rowptr[n];

    float wt[NT];
    {
        float inv = 1.f / fmaxf((float)deg, 1.f);
#pragma unroll
        for (int t = 0; t < NT; t++) wt[t] = inv * (float)hist[n * NT + t];
    }
    float attv[NH];
#pragma unroll
    for (int h = 0; h < NH; h++) attv[h] = att[h * DH + tid];
#pragma unroll
    for (int c = tid; c < HD; c += 256) xrs[c] = xr[(size_t)n * HD + c];
    __syncthreads();

    for (int i = 0; i < m; i++) {
        const bool isloop = (i == deg);
        int s, a = 0;
        if (isloop) { s = n; }
        else { int e = csr[r0 + i]; s = src[e]; a = attr[e]; }
        if (tid == 0 && i < CAP) ssrc[i] = s;
        const float* xlp = xl + (size_t)s * HD;
        float contrib[NH];
#pragma unroll
        for (int h = 0; h < NH; h++) {
            int c = h * DH + tid;
            float ee;
            if (isloop) {
                ee = wt[0] * E5[c] + wt[1] * E5[HD + c] + wt[2] * E5[2 * HD + c]
                   + wt[3] * E5[3 * HD + c] + wt[4] * E5[4 * HD + c];
            } else {
                ee = E5[(size_t)a * HD + c];
            }
            float z = xlp[c] + xrs[c] + ee;
            z = (z >= 0.f) ? z : NEG * z;
            contrib[h] = z * attv[h];
        }
#pragma unroll
        for (int h = 0; h < NH; h++) {
            float v = contrib[h];
            for (int off = 32; off; off >>= 1) v += __shfl_down(v, off, 64);
            if (lane == 0) part[w][h] = v;
        }
        __syncthreads();
        if (tid < NH) {
            float l = part[0][tid] + part[1][tid] + part[2][tid] + part[3][tid];
            if (i < CAP) lg[i][tid] = l;
            else {
                int eid = isloop ? (N_EDGES + n) : csr[r0 + i];
                glog[(size_t)eid * NH + tid] = l;
            }
        }
        __syncthreads();
    }

    if (tid < NH) {
        float mx = -1e30f;
        for (int i = 0; i < m; i++) {
            float l;
            if (i < CAP) l = lg[i][tid];
            else {
                int eid = (i < deg) ? csr[r0 + i] : (N_EDGES + n);
                l = glog[(size_t)eid * NH + tid];
            }
            mx = fmaxf(mx, l);
        }
        float sm = 0.f;
        for (int i = 0; i < m; i++) {
            float l;
            if (i < CAP) l = lg[i][tid];
            else {
                int eid = (i < deg) ? csr[r0 + i] : (N_EDGES + n);
                l = glog[(size_t)eid * NH + tid];
            }
            sm += expf(l - mx);
        }
        lmax[tid] = mx;
        denom[tid] = sm;
    }
    __syncthreads();

    for (int idx = tid; idx < m * NH; idx += 256) {
        int i = idx >> 3, hh = idx & 7;
        if (i < CAP) {
            lg[i][hh] = expf(lg[i][hh] - lmax[hh]) / denom[hh];
        } else {
            int eid = (i < deg) ? csr[r0 + i] : (N_EDGES + n);
            size_t p = (size_t)eid * NH + hh;
            glog[p] = expf(glog[p] - lmax[hh]) / denom[hh];
        }
    }
    __syncthreads();

    const int h = tid >> 5, cb = tid & 31;
    float acc[8] = {0.f, 0.f, 0.f, 0.f, 0.f, 0.f, 0.f, 0.f};
    for (int i = 0; i < m; i++) {
        int s;
        float al;
        if (i < CAP) { s = ssrc[i]; al = lg[i][h]; }
        else {
            int eid = (i < deg) ? csr[r0 + i] : (N_EDGES + n);
            s = (i < deg) ? src[eid] : n;
            al = glog[(size_t)eid * NH + h];
        }
        const float* xp = xl + (size_t)s * HD + h * DH + cb * 8;
        float4 v0 = *(const float4*)xp;
        float4 v1 = *(const float4*)(xp + 4);
        acc[0] += al * v0.x; acc[1] += al * v0.y;
        acc[2] += al * v0.z; acc[3] += al * v0.w;
        acc[4] += al * v1.x; acc[5] += al * v1.y;
        acc[6] += al * v1.z; acc[7] += al * v1.w;
    }
#pragma unroll
    for (int j = 0; j < 8; j++) outs[h][cb * 8 + j] = acc[j];
    __syncthreads();
    float o = 0.f;
#pragma unroll
    for (int hh = 0; hh < NH; hh++) o += outs[hh][tid];
    o = o * 0.125f + bgat[tid];
    hout[(size_t)n * DH + tid] = fmaxf(o, 0.f);
}

// ---------------------------------------------------------------------------
extern "C" void kernel_launch(void* const* d_in, const int* in_sizes, int n_in,
                              void* d_out, int out_size, void* d_ws, size_t ws_size,
                              hipStream_t stream)
{
    const float* x     = (const float*)d_in[0];
    const int*   eidx  = (const int*)d_in[1];
    const int*   src   = eidx;
    const int*   dst   = eidx + N_EDGES;
    const int*   attr  = (const int*)d_in[2];
    const int*   types = (const int*)d_in[3];
    const float* W_in  = (const float*)d_in[4];
    const float* b_in  = (const float*)d_in[5];
    const float* nemb  = (const float*)d_in[6];
    const float* eemb  = (const float*)d_in[7];
    const float* Wl    = (const float*)d_in[8];
    const float* bl    = (const float*)d_in[9];
    const float* Wr    = (const float*)d_in[10];
    const float* br    = (const float*)d_in[11];
    const float* We    = (const float*)d_in[12];
    const float* att   = (const float*)d_in[13];
    const float* bgat  = (const float*)d_in[14];
    const float* W_out = (const float*)d_in[15];
    const float* b_out = (const float*)d_in[16];
    float* out = (float*)d_out;

    char* ws = (char*)d_ws;
    size_t off = 0;
    auto alloc = [&](size_t bytes) -> void* {
        void* p = ws + off;
        off += (bytes + 255) & ~(size_t)255;
        return p;
    };
    float* h      = (float*)alloc((size_t)N_NODES * DH * 4);
    float* xl     = (float*)alloc((size_t)N_NODES * HD * 4);
    float* xr     = (float*)alloc((size_t)N_NODES * HD * 4);
    float* glog   = (float*)alloc((size_t)E2 * NH * 4);
    float* E5     = (float*)alloc((size_t)NT * HD * 4);
    int* cnt      = (int*)alloc((size_t)N_NODES * 4);
    int* hist     = (int*)alloc((size_t)N_NODES * NT * 4);
    int* rowptr   = (int*)alloc((size_t)(N_NODES + 1) * 4);
    int* fillc    = (int*)alloc((size_t)N_NODES * 4);
    int* csr      = (int*)alloc((size_t)N_EDGES * 4);
    unsigned short* A3  = (unsigned short*)alloc((size_t)N_NODES * 3 * D_IN * 2); // 50 MB (reused)
    unsigned short* B3T = (unsigned short*)alloc((size_t)HD * 3 * D_IN * 2);      // big enough for all

    hipMemsetAsync(cnt, 0, (size_t)N_NODES * 4, stream);
    hipMemsetAsync(hist, 0, (size_t)N_NODES * NT * 4, stream);
    hipMemsetAsync(fillc, 0, (size_t)N_NODES * 4, stream);

    deg_hist<<<(N_EDGES + 255) / 256, 256, 0, stream>>>(dst, attr, cnt, hist);
    scan_kernel<<<1, 256, 0, stream>>>(cnt, rowptr);
    csr_fill<<<(N_EDGES + 255) / 256, 256, 0, stream>>>(dst, rowptr, fillc, csr);

    // h = x @ W_in + b_in + node_emb[types]   (split-bf16 MFMA, K3 = 3*1024)
    split_act<<<(N_NODES * D_IN) / 256, 256, 0, stream>>>(x, A3, N_NODES * D_IN, 10);
    split_w<<<dim3(DH / 32, D_IN / 32), 256, 0, stream>>>(W_in, B3T, D_IN, DH);
    gemm_mfma<<<dim3(DH / 128, N_NODES / 128), 256, 0, stream>>>(
        A3, B3T, b_in, h, N_NODES, DH, 3 * D_IN, nemb, types);

    for (int l = 0; l < NL; l++) {
        const float* Wl_l = Wl + (size_t)l * DH * HD;
        const float* Wr_l = Wr + (size_t)l * DH * HD;
        const float* We_l = We + (size_t)l * DH * HD;

        split_act<<<(N_NODES * DH) / 256, 256, 0, stream>>>(h, A3, N_NODES * DH, 8);
        split_w<<<dim3(HD / 32, DH / 32), 256, 0, stream>>>(Wl_l, B3T, DH, HD);
        gemm_mfma<<<dim3(HD / 128, N_NODES / 128), 256, 0, stream>>>(
            A3, B3T, bl + (size_t)l * HD, xl, N_NODES, HD, 3 * DH, nullptr, nullptr);
        split_w<<<dim3(HD / 32, DH / 32), 256, 0, stream>>>(Wr_l, B3T, DH, HD);
        gemm_mfma<<<dim3(HD / 128, N_NODES / 128), 256, 0, stream>>>(
            A3, B3T, br + (size_t)l * HD, xr, N_NODES, HD, 3 * DH, nullptr, nullptr);

        e5_kernel<<<dim3(HD / 256, NT), 256, 0, stream>>>(eemb, We_l, E5);
        gat_fused<<<N_NODES, 256, 0, stream>>>(
            xl, xr, E5, att + (size_t)l * NH * DH, csr, rowptr, cnt, src, attr,
            hist, bgat + (size_t)l * DH, glog, h);
    }

    // out = h @ W_out + b_out
    split_act<<<(N_NODES * DH) / 256, 256, 0, stream>>>(h, A3, N_NODES * DH, 8);
    split_w<<<dim3(DH / 32, DH / 32), 256, 0, stream>>>(W_out, B3T, DH, DH);
    gemm_mfma<<<dim3(DH / 128, N_NODES / 128), 256, 0, stream>>>(
        A3, B3T, b_out, out, N_NODES, DH, 3 * DH, nullptr, nullptr);
}

// Round 6
// 895.894 us; speedup vs baseline: 1.6774x; 1.3046x over previous
//
#include <hip/hip_runtime.h>

#define N_NODES 8192
#define N_EDGES 32768
#define D_IN    1024
#define DH      256
#define NH      8
#define HD      2048   /* NH*DH */
#define NL      3
#define NT      5
#define NEG     0.2f
#define PADK    40     /* LDS row stride in bf16 elems (80 B -> 2-way bank alias, free) */

typedef __bf16 bf16x8 __attribute__((ext_vector_type(8)));
typedef float  f32x4  __attribute__((ext_vector_type(4)));
typedef unsigned short ushort8 __attribute__((ext_vector_type(8)));

static __device__ __forceinline__ unsigned short f2bf(float f) {
    unsigned u = __float_as_uint(f);
    unsigned r = (u + 0x7FFFu + ((u >> 16) & 1u)) >> 16;
    return (unsigned short)r;
}
static __device__ __forceinline__ float bf2f(unsigned short h) {
    return __uint_as_float(((unsigned)h) << 16);
}

// -------------------------------------------------- activation split (hi|hi|lo)
__global__ __launch_bounds__(256) void split_act(
    const float* __restrict__ X, unsigned short* __restrict__ A3,
    int MK, int kshift)
{
    int idx = blockIdx.x * 256 + threadIdx.x;
    if (idx >= MK) return;
    int K = 1 << kshift;
    int m = idx >> kshift, k = idx & (K - 1);
    float v = X[idx];
    unsigned short hu = f2bf(v);
    unsigned short lu = f2bf(v - bf2f(hu));
    size_t b = (size_t)m * 3 * K + k;
    A3[b]         = hu;
    A3[b + K]     = hu;
    A3[b + 2 * K] = lu;
}

// -------------------------------------------- weight split+transpose (hi;lo;hi)
__global__ __launch_bounds__(256) void split_w(
    const float* __restrict__ W, unsigned short* __restrict__ B3T,
    int K, int N)
{
    __shared__ float t[32][33];
    int k0 = blockIdx.y * 32, n0 = blockIdx.x * 32;
    int tid = threadIdx.x;
    int r = tid >> 5, c = tid & 31;
    for (int rr = r; rr < 32; rr += 8)
        t[rr][c] = W[(size_t)(k0 + rr) * N + n0 + c];
    __syncthreads();
    for (int rr = r; rr < 32; rr += 8) {
        int n = n0 + rr, k = k0 + c;
        float v = t[c][rr];
        unsigned short hu = f2bf(v);
        unsigned short lu = f2bf(v - bf2f(hu));
        size_t b = (size_t)n * 3 * K + k;
        B3T[b]         = hu;
        B3T[b + K]     = lu;
        B3T[b + 2 * K] = hu;
    }
}

// --------------------------------------------------------- MFMA GEMM 128x128
__global__ __launch_bounds__(256) void gemm_mfma(
    const unsigned short* __restrict__ A3, const unsigned short* __restrict__ B3T,
    const float* __restrict__ bias, float* __restrict__ C,
    int M, int N, int K3,
    const float* __restrict__ emb, const int* __restrict__ types)
{
    __shared__ unsigned short aLds[128 * PADK];
    __shared__ unsigned short bLds[128 * PADK];
    const int tid = threadIdx.x;
    const int m0 = blockIdx.y * 128, n0 = blockIdx.x * 128;
    const int lane = tid & 63, wid = tid >> 6;
    const int wm = wid >> 1, wn = wid & 1;
    const int srow = tid >> 2, scq = (tid & 3) * 8;
    const int frow = lane & 15, fkq = (lane >> 4) * 8;

    f32x4 acc[4][4] = {};

    for (int kt = 0; kt < K3; kt += 32) {
#pragma unroll
        for (int rnd = 0; rnd < 2; rnd++) {
            int row = rnd * 64 + srow;
            ushort8 av = *(const ushort8*)(A3 + (size_t)(m0 + row) * K3 + kt + scq);
            ushort8 bv = *(const ushort8*)(B3T + (size_t)(n0 + row) * K3 + kt + scq);
            *(ushort8*)(aLds + row * PADK + scq) = av;
            *(ushort8*)(bLds + row * PADK + scq) = bv;
        }
        __syncthreads();
        bf16x8 af[4], bf[4];
#pragma unroll
        for (int f = 0; f < 4; f++) {
            af[f] = *(const bf16x8*)(aLds + (wm * 64 + f * 16 + frow) * PADK + fkq);
            bf[f] = *(const bf16x8*)(bLds + (wn * 64 + f * 16 + frow) * PADK + fkq);
        }
#pragma unroll
        for (int i = 0; i < 4; i++)
#pragma unroll
            for (int j = 0; j < 4; j++)
                acc[i][j] = __builtin_amdgcn_mfma_f32_16x16x32_bf16(
                    af[i], bf[j], acc[i][j], 0, 0, 0);
        __syncthreads();
    }

    const int ccol = lane & 15, crq = (lane >> 4) * 4;
#pragma unroll
    for (int j = 0; j < 4; j++) {
        int gcol = n0 + wn * 64 + j * 16 + ccol;
        float bv = bias[gcol];
#pragma unroll
        for (int i = 0; i < 4; i++) {
#pragma unroll
            for (int r = 0; r < 4; r++) {
                int grow = m0 + wm * 64 + i * 16 + crq + r;
                float v = acc[i][j][r] + bv;
                if (emb) v += emb[types[grow] * DH + gcol];
                C[(size_t)grow * N + gcol] = v;
            }
        }
    }
}

// ------------------------------------------------------- E5 = edge_emb @ We
__global__ __launch_bounds__(256) void e5_kernel(
    const float* __restrict__ eemb, const float* __restrict__ We,
    float* __restrict__ E5)
{
    int col = blockIdx.x * 256 + threadIdx.x;
    int t = blockIdx.y;
    float acc = 0.f;
    for (int k = 0; k < DH; k++) acc += eemb[t * DH + k] * We[(size_t)k * HD + col];
    E5[(size_t)t * HD + col] = acc;
}

// ------------------------------------------------------- degree + attr hist
__global__ void deg_hist(const int* __restrict__ dst, const int* __restrict__ attr,
                         int* cnt, int* hist)
{
    int e = blockIdx.x * 256 + threadIdx.x;
    if (e < N_EDGES) {
        int d = dst[e];
        atomicAdd(&cnt[d], 1);
        atomicAdd(&hist[d * NT + attr[e]], 1);
    }
}

// ----------------------------------------------------------- rowptr scan
__global__ __launch_bounds__(256) void scan_kernel(const int* __restrict__ cnt,
                                                   int* __restrict__ rowptr)
{
    __shared__ int part[256];
    int tid = threadIdx.x;
    int base = tid * 32, s = 0;
    for (int i = 0; i < 32; i++) s += cnt[base + i];
    part[tid] = s;
    __syncthreads();
    for (int off = 1; off < 256; off <<= 1) {
        int v = (tid >= off) ? part[tid - off] : 0;
        __syncthreads();
        part[tid] += v;
        __syncthreads();
    }
    int run = (tid == 0) ? 0 : part[tid - 1];
    for (int i = 0; i < 32; i++) { rowptr[base + i] = run; run += cnt[base + i]; }
    if (tid == 255) rowptr[N_NODES] = run;
}

// ----------------------------------------------------------- CSR fill
__global__ void csr_fill(const int* __restrict__ dst, const int* __restrict__ rowptr,
                         int* fillc, int* __restrict__ csr)
{
    int e = blockIdx.x * 256 + threadIdx.x;
    if (e < N_EDGES) {
        int d = dst[e];
        int p = atomicAdd(&fillc[d], 1);
        csr[rowptr[d] + p] = e;
    }
}

// ------------- single-pass online-softmax GAT layer (one block per node)
// thread (h=tid>>5, cb=tid&31) owns channels [h*DH + cb*8 .. +8)
__global__ __launch_bounds__(256) void gat_online(
    const float* __restrict__ xl, const float* __restrict__ xr,
    const float* __restrict__ E5, const float* __restrict__ att,
    const int* __restrict__ csr, const int* __restrict__ rowptr,
    const int* __restrict__ cnt, const int* __restrict__ src,
    const int* __restrict__ attr, const int* __restrict__ hist,
    const float* __restrict__ bgat, float* __restrict__ hout)
{
    const int n = blockIdx.x, tid = threadIdx.x;
    const int h = tid >> 5, cb = tid & 31;
    const int base = h * DH + cb * 8;
    __shared__ float outs[NH][DH];

    const int deg = cnt[n];
    const int r0 = rowptr[n];

    // register-resident slices: xr[n], att
    float4 xr0 = *(const float4*)(xr + (size_t)n * HD + base);
    float4 xr1 = *(const float4*)(xr + (size_t)n * HD + base + 4);
    float4 at0 = *(const float4*)(att + base);
    float4 at1 = *(const float4*)(att + base + 4);

    float m = -1e30f, d = 0.f;
    float O0 = 0.f, O1 = 0.f, O2 = 0.f, O3 = 0.f;
    float O4 = 0.f, O5 = 0.f, O6 = 0.f, O7 = 0.f;

    for (int i = 0; i <= deg; i++) {
        const bool isloop = (i == deg);
        int s, a = 0;
        if (isloop) { s = n; }
        else { int e = csr[r0 + i]; s = src[e]; a = attr[e]; }

        const float* xp = xl + (size_t)s * HD + base;
        float4 v0 = *(const float4*)xp;
        float4 v1 = *(const float4*)(xp + 4);

        float4 e0, e1;
        if (isloop) {
            float inv = 1.f / fmaxf((float)deg, 1.f);
            e0 = make_float4(0.f, 0.f, 0.f, 0.f);
            e1 = make_float4(0.f, 0.f, 0.f, 0.f);
#pragma unroll
            for (int t = 0; t < NT; t++) {
                float wt = inv * (float)hist[n * NT + t];
                float4 q0 = *(const float4*)(E5 + (size_t)t * HD + base);
                float4 q1 = *(const float4*)(E5 + (size_t)t * HD + base + 4);
                e0.x += wt * q0.x; e0.y += wt * q0.y; e0.z += wt * q0.z; e0.w += wt * q0.w;
                e1.x += wt * q1.x; e1.y += wt * q1.y; e1.z += wt * q1.z; e1.w += wt * q1.w;
            }
        } else {
            e0 = *(const float4*)(E5 + (size_t)a * HD + base);
            e1 = *(const float4*)(E5 + (size_t)a * HD + base + 4);
        }

        // leaky-relu'd z dotted with att (this thread's 8-channel partial)
        float z, lsum = 0.f;
        z = v0.x + xr0.x + e0.x; z = (z >= 0.f) ? z : NEG * z; lsum += z * at0.x;
        z = v0.y + xr0.y + e0.y; z = (z >= 0.f) ? z : NEG * z; lsum += z * at0.y;
        z = v0.z + xr0.z + e0.z; z = (z >= 0.f) ? z : NEG * z; lsum += z * at0.z;
        z = v0.w + xr0.w + e0.w; z = (z >= 0.f) ? z : NEG * z; lsum += z * at0.w;
        z = v1.x + xr1.x + e1.x; z = (z >= 0.f) ? z : NEG * z; lsum += z * at1.x;
        z = v1.y + xr1.y + e1.y; z = (z >= 0.f) ? z : NEG * z; lsum += z * at1.y;
        z = v1.z + xr1.z + e1.z; z = (z >= 0.f) ? z : NEG * z; lsum += z * at1.z;
        z = v1.w + xr1.w + e1.w; z = (z >= 0.f) ? z : NEG * z; lsum += z * at1.w;

        // logit = reduce over the 32 lanes of this head group
#pragma unroll
        for (int off = 16; off; off >>= 1) lsum += __shfl_xor(lsum, off, 32);

        // online softmax update
        float nm = fmaxf(m, lsum);
        float scale = __expf(m - nm);
        float p = __expf(lsum - nm);
        O0 = O0 * scale + p * v0.x; O1 = O1 * scale + p * v0.y;
        O2 = O2 * scale + p * v0.z; O3 = O3 * scale + p * v0.w;
        O4 = O4 * scale + p * v1.x; O5 = O5 * scale + p * v1.y;
        O6 = O6 * scale + p * v1.z; O7 = O7 * scale + p * v1.w;
        d = d * scale + p;
        m = nm;
    }

    float invd = 1.f / d;
    float4 w0 = make_float4(O0 * invd, O1 * invd, O2 * invd, O3 * invd);
    float4 w1 = make_float4(O4 * invd, O5 * invd, O6 * invd, O7 * invd);
    *(float4*)(&outs[h][cb * 8])     = w0;
    *(float4*)(&outs[h][cb * 8 + 4]) = w1;
    __syncthreads();

    float o = 0.f;
#pragma unroll
    for (int hh = 0; hh < NH; hh++) o += outs[hh][tid];
    o = o * 0.125f + bgat[tid];
    hout[(size_t)n * DH + tid] = fmaxf(o, 0.f);
}

// ---------------------------------------------------------------------------
extern "C" void kernel_launch(void* const* d_in, const int* in_sizes, int n_in,
                              void* d_out, int out_size, void* d_ws, size_t ws_size,
                              hipStream_t stream)
{
    const float* x     = (const float*)d_in[0];
    const int*   eidx  = (const int*)d_in[1];
    const int*   src   = eidx;
    const int*   dst   = eidx + N_EDGES;
    const int*   attr  = (const int*)d_in[2];
    const int*   types = (const int*)d_in[3];
    const float* W_in  = (const float*)d_in[4];
    const float* b_in  = (const float*)d_in[5];
    const float* nemb  = (const float*)d_in[6];
    const float* eemb  = (const float*)d_in[7];
    const float* Wl    = (const float*)d_in[8];
    const float* bl    = (const float*)d_in[9];
    const float* Wr    = (const float*)d_in[10];
    const float* br    = (const float*)d_in[11];
    const float* We    = (const float*)d_in[12];
    const float* att   = (const float*)d_in[13];
    const float* bgat  = (const float*)d_in[14];
    const float* W_out = (const float*)d_in[15];
    const float* b_out = (const float*)d_in[16];
    float* out = (float*)d_out;

    char* ws = (char*)d_ws;
    size_t off = 0;
    auto alloc = [&](size_t bytes) -> void* {
        void* p = ws + off;
        off += (bytes + 255) & ~(size_t)255;
        return p;
    };
    float* h      = (float*)alloc((size_t)N_NODES * DH * 4);
    float* xl     = (float*)alloc((size_t)N_NODES * HD * 4);
    float* xr     = (float*)alloc((size_t)N_NODES * HD * 4);
    float* E5     = (float*)alloc((size_t)NT * HD * 4);
    int* cnt      = (int*)alloc((size_t)N_NODES * 4);
    int* hist     = (int*)alloc((size_t)N_NODES * NT * 4);
    int* rowptr   = (int*)alloc((size_t)(N_NODES + 1) * 4);
    int* fillc    = (int*)alloc((size_t)N_NODES * 4);
    int* csr      = (int*)alloc((size_t)N_EDGES * 4);
    unsigned short* A3  = (unsigned short*)alloc((size_t)N_NODES * 3 * D_IN * 2);
    unsigned short* B3T = (unsigned short*)alloc((size_t)HD * 3 * D_IN * 2);

    hipMemsetAsync(cnt, 0, (size_t)N_NODES * 4, stream);
    hipMemsetAsync(hist, 0, (size_t)N_NODES * NT * 4, stream);
    hipMemsetAsync(fillc, 0, (size_t)N_NODES * 4, stream);

    deg_hist<<<(N_EDGES + 255) / 256, 256, 0, stream>>>(dst, attr, cnt, hist);
    scan_kernel<<<1, 256, 0, stream>>>(cnt, rowptr);
    csr_fill<<<(N_EDGES + 255) / 256, 256, 0, stream>>>(dst, rowptr, fillc, csr);

    // h = x @ W_in + b_in + node_emb[types]
    split_act<<<(N_NODES * D_IN) / 256, 256, 0, stream>>>(x, A3, N_NODES * D_IN, 10);
    split_w<<<dim3(DH / 32, D_IN / 32), 256, 0, stream>>>(W_in, B3T, D_IN, DH);
    gemm_mfma<<<dim3(DH / 128, N_NODES / 128), 256, 0, stream>>>(
        A3, B3T, b_in, h, N_NODES, DH, 3 * D_IN, nemb, types);

    for (int l = 0; l < NL; l++) {
        const float* Wl_l = Wl + (size_t)l * DH * HD;
        const float* Wr_l = Wr + (size_t)l * DH * HD;
        const float* We_l = We + (size_t)l * DH * HD;

        split_act<<<(N_NODES * DH) / 256, 256, 0, stream>>>(h, A3, N_NODES * DH, 8);
        split_w<<<dim3(HD / 32, DH / 32), 256, 0, stream>>>(Wl_l, B3T, DH, HD);
        gemm_mfma<<<dim3(HD / 128, N_NODES / 128), 256, 0, stream>>>(
            A3, B3T, bl + (size_t)l * HD, xl, N_NODES, HD, 3 * DH, nullptr, nullptr);
        split_w<<<dim3(HD / 32, DH / 32), 256, 0, stream>>>(Wr_l, B3T, DH, HD);
        gemm_mfma<<<dim3(HD / 128, N_NODES / 128), 256, 0, stream>>>(
            A3, B3T, br + (size_t)l * HD, xr, N_NODES, HD, 3 * DH, nullptr, nullptr);

        e5_kernel<<<dim3(HD / 256, NT), 256, 0, stream>>>(eemb, We_l, E5);
        gat_online<<<N_NODES, 256, 0, stream>>>(
            xl, xr, E5, att + (size_t)l * NH * DH, csr, rowptr, cnt, src, attr,
            hist, bgat + (size_t)l * DH, h);
    }

    // out = h @ W_out + b_out
    split_act<<<(N_NODES * DH) / 256, 256, 0, stream>>>(h, A3, N_NODES * DH, 8);
    split_w<<<dim3(DH / 32, DH / 32), 256, 0, stream>>>(W_out, B3T, DH, DH);
    gemm_mfma<<<dim3(DH / 128, N_NODES / 128), 256, 0, stream>>>(
        A3, B3T, b_out, out, N_NODES, DH, 3 * DH, nullptr, nullptr);
}

// Round 10
// 804.960 us; speedup vs baseline: 1.8669x; 1.1130x over previous
//
#include <hip/hip_runtime.h>

#define N_NODES 8192
#define N_EDGES 32768
#define D_IN    1024
#define DH      256
#define NH      8
#define HD      2048   /* NH*DH */
#define NL      3
#define NT      5
#define NEG     0.2f

typedef __bf16 bf16x8 __attribute__((ext_vector_type(8)));
typedef float  f32x4  __attribute__((ext_vector_type(4)));
typedef unsigned short ushort8 __attribute__((ext_vector_type(8)));

static __device__ __forceinline__ unsigned short f2bf(float f) {
    unsigned u = __float_as_uint(f);
    unsigned r = (u + 0x7FFFu + ((u >> 16) & 1u)) >> 16;
    return (unsigned short)r;
}
static __device__ __forceinline__ float bf2f(unsigned short h) {
    return __uint_as_float(((unsigned)h) << 16);
}
static __device__ __forceinline__ void gload_lds16(const void* g, void* l) {
    __builtin_amdgcn_global_load_lds(
        (const __attribute__((address_space(1))) unsigned*)g,
        (__attribute__((address_space(3))) unsigned*)l, 16, 0, 0);
}

// ---------------------------------------------- activation split (hi|hi|lo) x8
// X fp32 [M,K] -> A3 bf16 [M,3K]; K8 = K/8 = 1<<k8shift
__global__ __launch_bounds__(256) void split_act8(
    const float* __restrict__ X, unsigned short* __restrict__ A3,
    int MK8, int k8shift)
{
    int idx = blockIdx.x * 256 + threadIdx.x;
    if (idx >= MK8) return;
    int K8 = 1 << k8shift;
    int K = K8 << 3;
    int m = idx >> k8shift, k8 = idx & (K8 - 1);
    const float* xp = X + (size_t)m * K + k8 * 8;
    float4 v0 = *(const float4*)xp;
    float4 v1 = *(const float4*)(xp + 4);
    float vv[8] = {v0.x, v0.y, v0.z, v0.w, v1.x, v1.y, v1.z, v1.w};
    ushort8 hi, lo;
#pragma unroll
    for (int j = 0; j < 8; j++) {
        unsigned short h = f2bf(vv[j]);
        hi[j] = h;
        lo[j] = f2bf(vv[j] - bf2f(h));
    }
    size_t b = (size_t)m * 3 * K + k8 * 8;
    *(ushort8*)(A3 + b)         = hi;
    *(ushort8*)(A3 + b + K)     = hi;
    *(ushort8*)(A3 + b + 2 * K) = lo;
}

// -------------------------------------------- weight split+transpose (hi;lo;hi)
__global__ __launch_bounds__(256) void split_w(
    const float* __restrict__ W, unsigned short* __restrict__ B3T,
    int K, int N)
{
    __shared__ float t[32][33];
    int k0 = blockIdx.y * 32, n0 = blockIdx.x * 32;
    int tid = threadIdx.x;
    int r = tid >> 5, c = tid & 31;
    for (int rr = r; rr < 32; rr += 8)
        t[rr][c] = W[(size_t)(k0 + rr) * N + n0 + c];
    __syncthreads();
    for (int rr = r; rr < 32; rr += 8) {
        int n = n0 + rr, k = k0 + c;
        float v = t[c][rr];
        unsigned short hu = f2bf(v);
        unsigned short lu = f2bf(v - bf2f(hu));
        size_t b = (size_t)n * 3 * K + k;
        B3T[b]         = hu;
        B3T[b + K]     = lu;
        B3T[b + 2 * K] = hu;
    }
}

// -------------------------------------- C pre-init (bias + optional type emb)
__global__ __launch_bounds__(256) void init_c(
    float* __restrict__ C, const float* __restrict__ bias, int MN, int nshift,
    const float* __restrict__ emb, const int* __restrict__ types)
{
    for (int idx = blockIdx.x * 256 + threadIdx.x; idx < MN; idx += gridDim.x * 256) {
        int col = idx & ((1 << nshift) - 1);
        float v = bias[col];
        if (emb) v += emb[types[idx >> nshift] * DH + col];
        C[idx] = v;
    }
}

// --------------------------------------------------------- MFMA GEMM 128x128
// BK=64, global_load_lds staging (linear LDS dest, pre-swizzled source,
// chunk-XOR swizzled fragment reads: chunk ^= row&7 -> 2-way banks, free).
// gridDim.z==1: C = A*B^T + bias.  gridDim.z>1: C += slice partial (atomic),
// C must be pre-initialized (init_c).
__global__ __launch_bounds__(256) void gemm_mfma(
    const unsigned short* __restrict__ A3, const unsigned short* __restrict__ B3T,
    const float* __restrict__ bias, float* __restrict__ C,
    int M, int N, int K3, int kslice)
{
    __shared__ unsigned short aLds[128 * 64];   // 16 KB, rows of 128 B
    __shared__ unsigned short bLds[128 * 64];
    const int tid = threadIdx.x;
    const int m0 = blockIdx.y * 128, n0 = blockIdx.x * 128;
    const int lane = tid & 63, w = tid >> 6;
    const int wm = w >> 1, wn = w & 1;
    const int srow8 = lane >> 3;          // row within 8-row staging group
    const int schunk = lane & 7;          // 16-B chunk 0..7
    const int frow = lane & 15, fchunk = lane >> 4;
    const int kt0 = blockIdx.z * kslice;
    const int kt1 = kt0 + kslice;

    f32x4 acc[4][4] = {};

    for (int kt = kt0; kt < kt1; kt += 64) {
        // stage A,B 128x64 tiles: 4 wave-rounds x 1 KB, lds dest linear,
        // global source pre-swizzled so read-side XOR sees logical data
#pragma unroll
        for (int q = 0; q < 4; q++) {
            int row = (q * 4 + w) * 8 + srow8;
            int scol = (schunk << 4) ^ ((row & 7) << 4);     // byte in row
            char* ldst_a = (char*)aLds + (q * 4 + w) * 1024;
            char* ldst_b = (char*)bLds + (q * 4 + w) * 1024;
            gload_lds16(A3 + (size_t)(m0 + row) * K3 + kt + (scol >> 1), ldst_a);
            gload_lds16(B3T + (size_t)(n0 + row) * K3 + kt + (scol >> 1), ldst_b);
        }
        __syncthreads();   // compiler drains vmcnt before barrier
#pragma unroll
        for (int kh = 0; kh < 2; kh++) {
            const int c = kh * 4 + fchunk;
            bf16x8 af[4], bfr[4];
#pragma unroll
            for (int f = 0; f < 4; f++) {
                int ra = wm * 64 + f * 16 + frow;
                af[f] = *(const bf16x8*)((const char*)aLds + ra * 128 + ((c ^ (ra & 7)) << 4));
                int rb = wn * 64 + f * 16 + frow;
                bfr[f] = *(const bf16x8*)((const char*)bLds + rb * 128 + ((c ^ (rb & 7)) << 4));
            }
#pragma unroll
            for (int i = 0; i < 4; i++)
#pragma unroll
                for (int j = 0; j < 4; j++)
                    acc[i][j] = __builtin_amdgcn_mfma_f32_16x16x32_bf16(
                        af[i], bfr[j], acc[i][j], 0, 0, 0);
        }
        __syncthreads();
    }

    const int ccol = lane & 15, crq = (lane >> 4) * 4;
    if (gridDim.z == 1) {
#pragma unroll
        for (int j = 0; j < 4; j++) {
            int gcol = n0 + wn * 64 + j * 16 + ccol;
            float bv = bias[gcol];
#pragma unroll
            for (int i = 0; i < 4; i++)
#pragma unroll
                for (int r = 0; r < 4; r++) {
                    int grow = m0 + wm * 64 + i * 16 + crq + r;
                    C[(size_t)grow * N + gcol] = acc[i][j][r] + bv;
                }
        }
    } else {
#pragma unroll
        for (int j = 0; j < 4; j++) {
            int gcol = n0 + wn * 64 + j * 16 + ccol;
#pragma unroll
            for (int i = 0; i < 4; i++)
#pragma unroll
                for (int r = 0; r < 4; r++) {
                    int grow = m0 + wm * 64 + i * 16 + crq + r;
                    atomicAdd(&C[(size_t)grow * N + gcol], acc[i][j][r]);
                }
        }
    }
}

// ------------------------------------------------------- E5 = edge_emb @ We
__global__ __launch_bounds__(256) void e5_kernel(
    const float* __restrict__ eemb, const float* __restrict__ We,
    float* __restrict__ E5)
{
    int col = blockIdx.x * 256 + threadIdx.x;
    int t = blockIdx.y;
    float acc = 0.f;
    for (int k = 0; k < DH; k++) acc += eemb[t * DH + k] * We[(size_t)k * HD + col];
    E5[(size_t)t * HD + col] = acc;
}

// ------------------------------------------------------- degree + attr hist
__global__ void deg_hist(const int* __restrict__ dst, const int* __restrict__ attr,
                         int* cnt, int* hist)
{
    int e = blockIdx.x * 256 + threadIdx.x;
    if (e < N_EDGES) {
        int d = dst[e];
        atomicAdd(&cnt[d], 1);
        atomicAdd(&hist[d * NT + attr[e]], 1);
    }
}

// ----------------------------------------------------------- rowptr scan
__global__ __launch_bounds__(256) void scan_kernel(const int* __restrict__ cnt,
                                                   int* __restrict__ rowptr)
{
    __shared__ int part[256];
    int tid = threadIdx.x;
    int base = tid * 32, s = 0;
    for (int i = 0; i < 32; i++) s += cnt[base + i];
    part[tid] = s;
    __syncthreads();
    for (int off = 1; off < 256; off <<= 1) {
        int v = (tid >= off) ? part[tid - off] : 0;
        __syncthreads();
        part[tid] += v;
        __syncthreads();
    }
    int run = (tid == 0) ? 0 : part[tid - 1];
    for (int i = 0; i < 32; i++) { rowptr[base + i] = run; run += cnt[base + i]; }
    if (tid == 255) rowptr[N_NODES] = run;
}

// ----------------------------------------------------------- CSR fill
__global__ void csr_fill(const int* __restrict__ dst, const int* __restrict__ rowptr,
                         int* fillc, int* __restrict__ csr)
{
    int e = blockIdx.x * 256 + threadIdx.x;
    if (e < N_EDGES) {
        int d = dst[e];
        int p = atomicAdd(&fillc[d], 1);
        csr[rowptr[d] + p] = e;
    }
}

// ------------- single-pass online-softmax GAT layer (one block per node)
__global__ __launch_bounds__(256) void gat_online(
    const float* __restrict__ xl, const float* __restrict__ xr,
    const float* __restrict__ E5, const float* __restrict__ att,
    const int* __restrict__ csr, const int* __restrict__ rowptr,
    const int* __restrict__ cnt, const int* __restrict__ src,
    const int* __restrict__ attr, const int* __restrict__ hist,
    const float* __restrict__ bgat, float* __restrict__ hout)
{
    const int n = blockIdx.x, tid = threadIdx.x;
    const int h = tid >> 5, cb = tid & 31;
    const int base = h * DH + cb * 8;
    __shared__ float outs[NH][DH];

    const int deg = cnt[n];
    const int r0 = rowptr[n];

    float4 xr0 = *(const float4*)(xr + (size_t)n * HD + base);
    float4 xr1 = *(const float4*)(xr + (size_t)n * HD + base + 4);
    float4 at0 = *(const float4*)(att + base);
    float4 at1 = *(const float4*)(att + base + 4);

    float m = -1e30f, d = 0.f;
    float O0 = 0.f, O1 = 0.f, O2 = 0.f, O3 = 0.f;
    float O4 = 0.f, O5 = 0.f, O6 = 0.f, O7 = 0.f;

    for (int i = 0; i <= deg; i++) {
        const bool isloop = (i == deg);
        int s, a = 0;
        if (isloop) { s = n; }
        else { int e = csr[r0 + i]; s = src[e]; a = attr[e]; }

        const float* xp = xl + (size_t)s * HD + base;
        float4 v0 = *(const float4*)xp;
        float4 v1 = *(const float4*)(xp + 4);

        float4 e0, e1;
        if (isloop) {
            float inv = 1.f / fmaxf((float)deg, 1.f);
            e0 = make_float4(0.f, 0.f, 0.f, 0.f);
            e1 = make_float4(0.f, 0.f, 0.f, 0.f);
#pragma unroll
            for (int t = 0; t < NT; t++) {
                float wt = inv * (float)hist[n * NT + t];
                float4 q0 = *(const float4*)(E5 + (size_t)t * HD + base);
                float4 q1 = *(const float4*)(E5 + (size_t)t * HD + base + 4);
                e0.x += wt * q0.x; e0.y += wt * q0.y; e0.z += wt * q0.z; e0.w += wt * q0.w;
                e1.x += wt * q1.x; e1.y += wt * q1.y; e1.z += wt * q1.z; e1.w += wt * q1.w;
            }
        } else {
            e0 = *(const float4*)(E5 + (size_t)a * HD + base);
            e1 = *(const float4*)(E5 + (size_t)a * HD + base + 4);
        }

        float z, lsum = 0.f;
        z = v0.x + xr0.x + e0.x; z = (z >= 0.f) ? z : NEG * z; lsum += z * at0.x;
        z = v0.y + xr0.y + e0.y; z = (z >= 0.f) ? z : NEG * z; lsum += z * at0.y;
        z = v0.z + xr0.z + e0.z; z = (z >= 0.f) ? z : NEG * z; lsum += z * at0.z;
        z = v0.w + xr0.w + e0.w; z = (z >= 0.f) ? z : NEG * z; lsum += z * at0.w;
        z = v1.x + xr1.x + e1.x; z = (z >= 0.f) ? z : NEG * z; lsum += z * at1.x;
        z = v1.y + xr1.y + e1.y; z = (z >= 0.f) ? z : NEG * z; lsum += z * at1.y;
        z = v1.z + xr1.z + e1.z; z = (z >= 0.f) ? z : NEG * z; lsum += z * at1.z;
        z = v1.w + xr1.w + e1.w; z = (z >= 0.f) ? z : NEG * z; lsum += z * at1.w;

#pragma unroll
        for (int off = 16; off; off >>= 1) lsum += __shfl_xor(lsum, off, 32);

        float nm = fmaxf(m, lsum);
        float scale = __expf(m - nm);
        float p = __expf(lsum - nm);
        O0 = O0 * scale + p * v0.x; O1 = O1 * scale + p * v0.y;
        O2 = O2 * scale + p * v0.z; O3 = O3 * scale + p * v0.w;
        O4 = O4 * scale + p * v1.x; O5 = O5 * scale + p * v1.y;
        O6 = O6 * scale + p * v1.z; O7 = O7 * scale + p * v1.w;
        d = d * scale + p;
        m = nm;
    }

    float invd = 1.f / d;
    float4 w0 = make_float4(O0 * invd, O1 * invd, O2 * invd, O3 * invd);
    float4 w1 = make_float4(O4 * invd, O5 * invd, O6 * invd, O7 * invd);
    *(float4*)(&outs[h][cb * 8])     = w0;
    *(float4*)(&outs[h][cb * 8 + 4]) = w1;
    __syncthreads();

    float o = 0.f;
#pragma unroll
    for (int hh = 0; hh < NH; hh++) o += outs[hh][tid];
    o = o * 0.125f + bgat[tid];
    hout[(size_t)n * DH + tid] = fmaxf(o, 0.f);
}

// ---------------------------------------------------------------------------
extern "C" void kernel_launch(void* const* d_in, const int* in_sizes, int n_in,
                              void* d_out, int out_size, void* d_ws, size_t ws_size,
                              hipStream_t stream)
{
    const float* x     = (const float*)d_in[0];
    const int*   eidx  = (const int*)d_in[1];
    const int*   src   = eidx;
    const int*   dst   = eidx + N_EDGES;
    const int*   attr  = (const int*)d_in[2];
    const int*   types = (const int*)d_in[3];
    const float* W_in  = (const float*)d_in[4];
    const float* b_in  = (const float*)d_in[5];
    const float* nemb  = (const float*)d_in[6];
    const float* eemb  = (const float*)d_in[7];
    const float* Wl    = (const float*)d_in[8];
    const float* bl    = (const float*)d_in[9];
    const float* Wr    = (const float*)d_in[10];
    const float* br    = (const float*)d_in[11];
    const float* We    = (const float*)d_in[12];
    const float* att   = (const float*)d_in[13];
    const float* bgat  = (const float*)d_in[14];
    const float* W_out = (const float*)d_in[15];
    const float* b_out = (const float*)d_in[16];
    float* out = (float*)d_out;

    char* ws = (char*)d_ws;
    size_t off = 0;
    auto alloc = [&](size_t bytes) -> void* {
        void* p = ws + off;
        off += (bytes + 255) & ~(size_t)255;
        return p;
    };
    float* h      = (float*)alloc((size_t)N_NODES * DH * 4);
    float* xl     = (float*)alloc((size_t)N_NODES * HD * 4);
    float* xr     = (float*)alloc((size_t)N_NODES * HD * 4);
    float* E5     = (float*)alloc((size_t)NT * HD * 4);
    int* cnt      = (int*)alloc((size_t)N_NODES * 4);
    int* hist     = (int*)alloc((size_t)N_NODES * NT * 4);
    int* rowptr   = (int*)alloc((size_t)(N_NODES + 1) * 4);
    int* fillc    = (int*)alloc((size_t)N_NODES * 4);
    int* csr      = (int*)alloc((size_t)N_EDGES * 4);
    unsigned short* A3  = (unsigned short*)alloc((size_t)N_NODES * 3 * D_IN * 2);
    unsigned short* B3T = (unsigned short*)alloc((size_t)HD * 3 * D_IN * 2);

    hipMemsetAsync(cnt, 0, (size_t)N_NODES * 4, stream);
    hipMemsetAsync(hist, 0, (size_t)N_NODES * NT * 4, stream);
    hipMemsetAsync(fillc, 0, (size_t)N_NODES * 4, stream);

    deg_hist<<<(N_EDGES + 255) / 256, 256, 0, stream>>>(dst, attr, cnt, hist);
    scan_kernel<<<1, 256, 0, stream>>>(cnt, rowptr);
    csr_fill<<<(N_EDGES + 255) / 256, 256, 0, stream>>>(dst, rowptr, fillc, csr);

    // h = x @ W_in + b_in + node_emb[types]   (split-K=8, atomic accumulate)
    split_act8<<<(N_NODES * D_IN / 8 + 255) / 256, 256, 0, stream>>>(
        x, A3, N_NODES * D_IN / 8, 7);
    split_w<<<dim3(DH / 32, D_IN / 32), 256, 0, stream>>>(W_in, B3T, D_IN, DH);
    init_c<<<2048, 256, 0, stream>>>(h, b_in, N_NODES * DH, 8, nemb, types);
    gemm_mfma<<<dim3(DH / 128, N_NODES / 128, 8), 256, 0, stream>>>(
        A3, B3T, nullptr, h, N_NODES, DH, 3 * D_IN, 3 * D_IN / 8);

    for (int l = 0; l < NL; l++) {
        const float* Wl_l = Wl + (size_t)l * DH * HD;
        const float* Wr_l = Wr + (size_t)l * DH * HD;
        const float* We_l = We + (size_t)l * DH * HD;

        split_act8<<<(N_NODES * DH / 8 + 255) / 256, 256, 0, stream>>>(
            h, A3, N_NODES * DH / 8, 5);
        split_w<<<dim3(HD / 32, DH / 32), 256, 0, stream>>>(Wl_l, B3T, DH, HD);
        gemm_mfma<<<dim3(HD / 128, N_NODES / 128, 1), 256, 0, stream>>>(
            A3, B3T, bl + (size_t)l * HD, xl, N_NODES, HD, 3 * DH, 3 * DH);
        split_w<<<dim3(HD / 32, DH / 32), 256, 0, stream>>>(Wr_l, B3T, DH, HD);
        gemm_mfma<<<dim3(HD / 128, N_NODES / 128, 1), 256, 0, stream>>>(
            A3, B3T, br + (size_t)l * HD, xr, N_NODES, HD, 3 * DH, 3 * DH);

        e5_kernel<<<dim3(HD / 256, NT), 256, 0, stream>>>(eemb, We_l, E5);
        gat_online<<<N_NODES, 256, 0, stream>>>(
            xl, xr, E5, att + (size_t)l * NH * DH, csr, rowptr, cnt, src, attr,
            hist, bgat + (size_t)l * DH, h);
    }

    // out = h @ W_out + b_out   (split-K=4, atomic accumulate)
    split_act8<<<(N_NODES * DH / 8 + 255) / 256, 256, 0, stream>>>(
        h, A3, N_NODES * DH / 8, 5);
    split_w<<<dim3(DH / 32, DH / 32), 256, 0, stream>>>(W_out, B3T, DH, DH);
    init_c<<<2048, 256, 0, stream>>>(out, b_out, N_NODES * DH, 8, nullptr, nullptr);
    gemm_mfma<<<dim3(DH / 128, N_NODES / 128, 4), 256, 0, stream>>>(
        A3, B3T, nullptr, out, N_NODES, DH, 3 * DH, 3 * DH / 4);
}

// Round 13
// 785.625 us; speedup vs baseline: 1.9128x; 1.0246x over previous
//
#include <hip/hip_runtime.h>

#define N_NODES 8192
#define N_EDGES 32768
#define D_IN    1024
#define DH      256
#define NH      8
#define HD      2048   /* NH*DH (per-node feature width) */
#define W2      4096   /* 2*HD: xl|xr merged row width */
#define NL      3
#define NT      5
#define NEG     0.2f

typedef __bf16 bf16x8 __attribute__((ext_vector_type(8)));
typedef float  f32x4  __attribute__((ext_vector_type(4)));
typedef unsigned short ushort8 __attribute__((ext_vector_type(8)));

static __device__ __forceinline__ unsigned short f2bf(float f) {
    unsigned u = __float_as_uint(f);
    unsigned r = (u + 0x7FFFu + ((u >> 16) & 1u)) >> 16;
    return (unsigned short)r;
}
static __device__ __forceinline__ float bf2f(unsigned short h) {
    return __uint_as_float(((unsigned)h) << 16);
}
static __device__ __forceinline__ void gload_lds16(const void* g, void* l) {
    __builtin_amdgcn_global_load_lds(
        (const __attribute__((address_space(1))) unsigned*)g,
        (__attribute__((address_space(3))) unsigned*)l, 16, 0, 0);
}

// ---------------------------------------------- activation split (hi|hi|lo) x8
__global__ __launch_bounds__(256) void split_act8(
    const float* __restrict__ X, unsigned short* __restrict__ A3,
    int MK8, int k8shift)
{
    int idx = blockIdx.x * 256 + threadIdx.x;
    if (idx >= MK8) return;
    int K8 = 1 << k8shift;
    int K = K8 << 3;
    int m = idx >> k8shift, k8 = idx & (K8 - 1);
    const float* xp = X + (size_t)m * K + k8 * 8;
    float4 v0 = *(const float4*)xp;
    float4 v1 = *(const float4*)(xp + 4);
    float vv[8] = {v0.x, v0.y, v0.z, v0.w, v1.x, v1.y, v1.z, v1.w};
    ushort8 hi, lo;
#pragma unroll
    for (int j = 0; j < 8; j++) {
        unsigned short h = f2bf(vv[j]);
        hi[j] = h;
        lo[j] = f2bf(vv[j] - bf2f(h));
    }
    size_t b = (size_t)m * 3 * K + k8 * 8;
    *(ushort8*)(A3 + b)         = hi;
    *(ushort8*)(A3 + b + K)     = hi;
    *(ushort8*)(A3 + b + 2 * K) = lo;
}

// -------------------------------------------- weight split+transpose (hi;lo;hi)
__global__ __launch_bounds__(256) void split_w(
    const float* __restrict__ W, unsigned short* __restrict__ B3T,
    int K, int N)
{
    __shared__ float t[32][33];
    int k0 = blockIdx.y * 32, n0 = blockIdx.x * 32;
    int tid = threadIdx.x;
    int r = tid >> 5, c = tid & 31;
    for (int rr = r; rr < 32; rr += 8)
        t[rr][c] = W[(size_t)(k0 + rr) * N + n0 + c];
    __syncthreads();
    for (int rr = r; rr < 32; rr += 8) {
        int n = n0 + rr, k = k0 + c;
        float v = t[c][rr];
        unsigned short hu = f2bf(v);
        unsigned short lu = f2bf(v - bf2f(hu));
        size_t b = (size_t)n * 3 * K + k;
        B3T[b]         = hu;
        B3T[b + K]     = lu;
        B3T[b + 2 * K] = hu;
    }
}

// -------------------------------------- C pre-init (bias + optional type emb)
__global__ __launch_bounds__(256) void init_c(
    float* __restrict__ C, const float* __restrict__ bias, int MN, int nshift,
    const float* __restrict__ emb, const int* __restrict__ types)
{
    for (int idx = blockIdx.x * 256 + threadIdx.x; idx < MN; idx += gridDim.x * 256) {
        int col = idx & ((1 << nshift) - 1);
        float v = bias[col];
        if (emb) v += emb[types[idx >> nshift] * DH + col];
        C[idx] = v;
    }
}

// --------------------------------------------------------- MFMA GEMM 128x128
// BK=64, global_load_lds staging (linear LDS dest, pre-swizzled source,
// chunk-XOR swizzled fragment reads). gridDim.z==1: C = A*B^T + bias (bias2
// for cols >= nsplit; block-aligned split so the branch is wave-uniform).
// gridDim.z>1: atomic accumulate into pre-initialized C.
__global__ __launch_bounds__(256) void gemm_mfma(
    const unsigned short* __restrict__ A3, const unsigned short* __restrict__ B3T,
    const float* __restrict__ bias, const float* __restrict__ bias2, int nsplit,
    float* __restrict__ C, int M, int N, int K3, int kslice)
{
    __shared__ unsigned short aLds[128 * 64];   // 16 KB, rows of 128 B
    __shared__ unsigned short bLds[128 * 64];
    const int tid = threadIdx.x;
    const int m0 = blockIdx.y * 128, n0 = blockIdx.x * 128;
    const int lane = tid & 63, w = tid >> 6;
    const int wm = w >> 1, wn = w & 1;
    const int srow8 = lane >> 3;
    const int schunk = lane & 7;
    const int frow = lane & 15, fchunk = lane >> 4;
    const int kt0 = blockIdx.z * kslice;
    const int kt1 = kt0 + kslice;

    f32x4 acc[4][4] = {};

    for (int kt = kt0; kt < kt1; kt += 64) {
#pragma unroll
        for (int q = 0; q < 4; q++) {
            int row = (q * 4 + w) * 8 + srow8;
            int scol = (schunk << 4) ^ ((row & 7) << 4);
            char* ldst_a = (char*)aLds + (q * 4 + w) * 1024;
            char* ldst_b = (char*)bLds + (q * 4 + w) * 1024;
            gload_lds16(A3 + (size_t)(m0 + row) * K3 + kt + (scol >> 1), ldst_a);
            gload_lds16(B3T + (size_t)(n0 + row) * K3 + kt + (scol >> 1), ldst_b);
        }
        __syncthreads();
#pragma unroll
        for (int kh = 0; kh < 2; kh++) {
            const int c = kh * 4 + fchunk;
            bf16x8 af[4], bfr[4];
#pragma unroll
            for (int f = 0; f < 4; f++) {
                int ra = wm * 64 + f * 16 + frow;
                af[f] = *(const bf16x8*)((const char*)aLds + ra * 128 + ((c ^ (ra & 7)) << 4));
                int rb = wn * 64 + f * 16 + frow;
                bfr[f] = *(const bf16x8*)((const char*)bLds + rb * 128 + ((c ^ (rb & 7)) << 4));
            }
#pragma unroll
            for (int i = 0; i < 4; i++)
#pragma unroll
                for (int j = 0; j < 4; j++)
                    acc[i][j] = __builtin_amdgcn_mfma_f32_16x16x32_bf16(
                        af[i], bfr[j], acc[i][j], 0, 0, 0);
        }
        __syncthreads();
    }

    const int ccol = lane & 15, crq = (lane >> 4) * 4;
    if (gridDim.z == 1) {
#pragma unroll
        for (int j = 0; j < 4; j++) {
            int gcol = n0 + wn * 64 + j * 16 + ccol;
            float bv = (gcol < nsplit) ? bias[gcol] : bias2[gcol - nsplit];
#pragma unroll
            for (int i = 0; i < 4; i++)
#pragma unroll
                for (int r = 0; r < 4; r++) {
                    int grow = m0 + wm * 64 + i * 16 + crq + r;
                    C[(size_t)grow * N + gcol] = acc[i][j][r] + bv;
                }
        }
    } else {
#pragma unroll
        for (int j = 0; j < 4; j++) {
            int gcol = n0 + wn * 64 + j * 16 + ccol;
#pragma unroll
            for (int i = 0; i < 4; i++)
#pragma unroll
                for (int r = 0; r < 4; r++) {
                    int grow = m0 + wm * 64 + i * 16 + crq + r;
                    atomicAdd(&C[(size_t)grow * N + gcol], acc[i][j][r]);
                }
        }
    }
}

// ------------------------------------------------------- E5 = edge_emb @ We
__global__ __launch_bounds__(256) void e5_kernel(
    const float* __restrict__ eemb, const float* __restrict__ We,
    float* __restrict__ E5)
{
    int col = blockIdx.x * 256 + threadIdx.x;
    int t = blockIdx.y;
    float acc = 0.f;
    for (int k = 0; k < DH; k++) acc += eemb[t * DH + k] * We[(size_t)k * HD + col];
    E5[(size_t)t * HD + col] = acc;
}

// ------------------------------------------------------- degree + attr hist
__global__ void deg_hist(const int* __restrict__ dst, const int* __restrict__ attr,
                         int* cnt, int* hist)
{
    int e = blockIdx.x * 256 + threadIdx.x;
    if (e < N_EDGES) {
        int d = dst[e];
        atomicAdd(&cnt[d], 1);
        atomicAdd(&hist[d * NT + attr[e]], 1);
    }
}

// ----------------------------------------------------------- rowptr scan
__global__ __launch_bounds__(256) void scan_kernel(const int* __restrict__ cnt,
                                                   int* __restrict__ rowptr)
{
    __shared__ int part[256];
    int tid = threadIdx.x;
    int base = tid * 32, s = 0;
    for (int i = 0; i < 32; i++) s += cnt[base + i];
    part[tid] = s;
    __syncthreads();
    for (int off = 1; off < 256; off <<= 1) {
        int v = (tid >= off) ? part[tid - off] : 0;
        __syncthreads();
        part[tid] += v;
        __syncthreads();
    }
    int run = (tid == 0) ? 0 : part[tid - 1];
    for (int i = 0; i < 32; i++) { rowptr[base + i] = run; run += cnt[base + i]; }
    if (tid == 255) rowptr[N_NODES] = run;
}

// ----------------------------------------------------------- CSR fill
__global__ void csr_fill(const int* __restrict__ dst, const int* __restrict__ rowptr,
                         int* fillc, int* __restrict__ csr)
{
    int e = blockIdx.x * 256 + threadIdx.x;
    if (e < N_EDGES) {
        int d = dst[e];
        int p = atomicAdd(&fillc[d], 1);
        csr[rowptr[d] + p] = e;
    }
}

// ------------- single-pass online-softmax GAT layer (one block per node)
// xlr[n] = [xl row | xr row] (W2 floats). 2-stage prefetch pipeline: edge
// i+1's csr/src/xl-row loads issue before edge i's compute.
__global__ __launch_bounds__(256) void gat_online(
    const float* __restrict__ xlr, const float* __restrict__ E5,
    const float* __restrict__ att, const int* __restrict__ csr,
    const int* __restrict__ rowptr, const int* __restrict__ cnt,
    const int* __restrict__ src, const int* __restrict__ attr,
    const int* __restrict__ hist, const float* __restrict__ bgat,
    float* __restrict__ hout)
{
    const int n = blockIdx.x, tid = threadIdx.x;
    const int h = tid >> 5, cb = tid & 31;
    const int base = h * DH + cb * 8;
    __shared__ float outs[NH][DH];

    const int deg = cnt[n];
    const int r0 = rowptr[n];

    // register-resident: xr slice (cols HD+base) and att slice
    float4 xr0 = *(const float4*)(xlr + (size_t)n * W2 + HD + base);
    float4 xr1 = *(const float4*)(xlr + (size_t)n * W2 + HD + base + 4);
    float4 at0 = *(const float4*)(att + base);
    float4 at1 = *(const float4*)(att + base + 4);

    float m = -1e30f, d = 0.f;
    float O0 = 0.f, O1 = 0.f, O2 = 0.f, O3 = 0.f;
    float O4 = 0.f, O5 = 0.f, O6 = 0.f, O7 = 0.f;

    // pipeline prologue: fetch edge 0 (a<0 marks the self loop)
    int a_c;
    int s_c;
    if (deg == 0) { s_c = n; a_c = -1; }
    else { int e0 = csr[r0]; s_c = src[e0]; a_c = attr[e0]; }
    const float* xp = xlr + (size_t)s_c * W2 + base;
    float4 v0 = *(const float4*)xp;
    float4 v1 = *(const float4*)(xp + 4);

    for (int i = 0; i <= deg; i++) {
        // prefetch edge i+1
        int a_n = 0;
        float4 n0 = make_float4(0.f, 0.f, 0.f, 0.f), n1 = n0;
        if (i < deg) {
            int s_n;
            if (i + 1 == deg) { s_n = n; a_n = -1; }
            else { int e = csr[r0 + i + 1]; s_n = src[e]; a_n = attr[e]; }
            const float* xq = xlr + (size_t)s_n * W2 + base;
            n0 = *(const float4*)xq;
            n1 = *(const float4*)(xq + 4);
        }

        float4 e0v, e1v;
        if (a_c < 0) {   // self loop: hist-weighted E5 mix
            float inv = 1.f / fmaxf((float)deg, 1.f);
            e0v = make_float4(0.f, 0.f, 0.f, 0.f);
            e1v = make_float4(0.f, 0.f, 0.f, 0.f);
#pragma unroll
            for (int t = 0; t < NT; t++) {
                float wt = inv * (float)hist[n * NT + t];
                float4 q0 = *(const float4*)(E5 + (size_t)t * HD + base);
                float4 q1 = *(const float4*)(E5 + (size_t)t * HD + base + 4);
                e0v.x += wt * q0.x; e0v.y += wt * q0.y; e0v.z += wt * q0.z; e0v.w += wt * q0.w;
                e1v.x += wt * q1.x; e1v.y += wt * q1.y; e1v.z += wt * q1.z; e1v.w += wt * q1.w;
            }
        } else {
            e0v = *(const float4*)(E5 + (size_t)a_c * HD + base);
            e1v = *(const float4*)(E5 + (size_t)a_c * HD + base + 4);
        }

        float z, lsum = 0.f;
        z = v0.x + xr0.x + e0v.x; z = (z >= 0.f) ? z : NEG * z; lsum += z * at0.x;
        z = v0.y + xr0.y + e0v.y; z = (z >= 0.f) ? z : NEG * z; lsum += z * at0.y;
        z = v0.z + xr0.z + e0v.z; z = (z >= 0.f) ? z : NEG * z; lsum += z * at0.z;
        z = v0.w + xr0.w + e0v.w; z = (z >= 0.f) ? z : NEG * z; lsum += z * at0.w;
        z = v1.x + xr1.x + e1v.x; z = (z >= 0.f) ? z : NEG * z; lsum += z * at1.x;
        z = v1.y + xr1.y + e1v.y; z = (z >= 0.f) ? z : NEG * z; lsum += z * at1.y;
        z = v1.z + xr1.z + e1v.z; z = (z >= 0.f) ? z : NEG * z; lsum += z * at1.z;
        z = v1.w + xr1.w + e1v.w; z = (z >= 0.f) ? z : NEG * z; lsum += z * at1.w;

#pragma unroll
        for (int off = 16; off; off >>= 1) lsum += __shfl_xor(lsum, off, 32);

        float nm = fmaxf(m, lsum);
        float scale = __expf(m - nm);
        float p = __expf(lsum - nm);
        O0 = O0 * scale + p * v0.x; O1 = O1 * scale + p * v0.y;
        O2 = O2 * scale + p * v0.z; O3 = O3 * scale + p * v0.w;
        O4 = O4 * scale + p * v1.x; O5 = O5 * scale + p * v1.y;
        O6 = O6 * scale + p * v1.z; O7 = O7 * scale + p * v1.w;
        d = d * scale + p;
        m = nm;

        v0 = n0; v1 = n1; a_c = a_n;
    }

    float invd = 1.f / d;
    float4 w0 = make_float4(O0 * invd, O1 * invd, O2 * invd, O3 * invd);
    float4 w1 = make_float4(O4 * invd, O5 * invd, O6 * invd, O7 * invd);
    *(float4*)(&outs[h][cb * 8])     = w0;
    *(float4*)(&outs[h][cb * 8 + 4]) = w1;
    __syncthreads();

    float o = 0.f;
#pragma unroll
    for (int hh = 0; hh < NH; hh++) o += outs[hh][tid];
    o = o * 0.125f + bgat[tid];
    hout[(size_t)n * DH + tid] = fmaxf(o, 0.f);
}

// ---------------------------------------------------------------------------
extern "C" void kernel_launch(void* const* d_in, const int* in_sizes, int n_in,
                              void* d_out, int out_size, void* d_ws, size_t ws_size,
                              hipStream_t stream)
{
    const float* x     = (const float*)d_in[0];
    const int*   eidx  = (const int*)d_in[1];
    const int*   src   = eidx;
    const int*   dst   = eidx + N_EDGES;
    const int*   attr  = (const int*)d_in[2];
    const int*   types = (const int*)d_in[3];
    const float* W_in  = (const float*)d_in[4];
    const float* b_in  = (const float*)d_in[5];
    const float* nemb  = (const float*)d_in[6];
    const float* eemb  = (const float*)d_in[7];
    const float* Wl    = (const float*)d_in[8];
    const float* bl    = (const float*)d_in[9];
    const float* Wr    = (const float*)d_in[10];
    const float* br    = (const float*)d_in[11];
    const float* We    = (const float*)d_in[12];
    const float* att   = (const float*)d_in[13];
    const float* bgat  = (const float*)d_in[14];
    const float* W_out = (const float*)d_in[15];
    const float* b_out = (const float*)d_in[16];
    float* out = (float*)d_out;

    char* ws = (char*)d_ws;
    size_t off = 0;
    auto alloc = [&](size_t bytes) -> void* {
        void* p = ws + off;
        off += (bytes + 255) & ~(size_t)255;
        return p;
    };
    float* h      = (float*)alloc((size_t)N_NODES * DH * 4);
    float* xlr    = (float*)alloc((size_t)N_NODES * W2 * 4);      // 128 MB
    float* E5     = (float*)alloc((size_t)NT * HD * 4);
    int* cnt      = (int*)alloc((size_t)N_NODES * 4);
    int* hist     = (int*)alloc((size_t)N_NODES * NT * 4);
    int* rowptr   = (int*)alloc((size_t)(N_NODES + 1) * 4);
    int* fillc    = (int*)alloc((size_t)N_NODES * 4);
    int* csr      = (int*)alloc((size_t)N_EDGES * 4);
    unsigned short* A3  = (unsigned short*)alloc((size_t)N_NODES * 3 * D_IN * 2);
    unsigned short* B3T = (unsigned short*)alloc((size_t)W2 * 3 * DH * 2 +
                                                 (size_t)DH * 3 * D_IN * 2);

    hipMemsetAsync(cnt, 0, (size_t)N_NODES * 4, stream);
    hipMemsetAsync(hist, 0, (size_t)N_NODES * NT * 4, stream);
    hipMemsetAsync(fillc, 0, (size_t)N_NODES * 4, stream);

    deg_hist<<<(N_EDGES + 255) / 256, 256, 0, stream>>>(dst, attr, cnt, hist);
    scan_kernel<<<1, 256, 0, stream>>>(cnt, rowptr);
    csr_fill<<<(N_EDGES + 255) / 256, 256, 0, stream>>>(dst, rowptr, fillc, csr);

    // h = x @ W_in + b_in + node_emb[types]   (split-K=8, atomic accumulate)
    split_act8<<<(N_NODES * D_IN / 8 + 255) / 256, 256, 0, stream>>>(
        x, A3, N_NODES * D_IN / 8, 7);
    split_w<<<dim3(DH / 32, D_IN / 32), 256, 0, stream>>>(W_in, B3T, D_IN, DH);
    init_c<<<2048, 256, 0, stream>>>(h, b_in, N_NODES * DH, 8, nemb, types);
    gemm_mfma<<<dim3(DH / 128, N_NODES / 128, 8), 256, 0, stream>>>(
        A3, B3T, nullptr, nullptr, DH, h, N_NODES, DH, 3 * D_IN, 3 * D_IN / 8);

    for (int l = 0; l < NL; l++) {
        const float* Wl_l = Wl + (size_t)l * DH * HD;
        const float* Wr_l = Wr + (size_t)l * DH * HD;
        const float* We_l = We + (size_t)l * DH * HD;

        split_act8<<<(N_NODES * DH / 8 + 255) / 256, 256, 0, stream>>>(
            h, A3, N_NODES * DH / 8, 5);
        // merged [Wl | Wr] -> B3T rows [0,HD) and [HD, 2*HD)
        split_w<<<dim3(HD / 32, DH / 32), 256, 0, stream>>>(Wl_l, B3T, DH, HD);
        split_w<<<dim3(HD / 32, DH / 32), 256, 0, stream>>>(
            Wr_l, B3T + (size_t)HD * 3 * DH, DH, HD);
        // xlr = h @ [Wl | Wr] + [bl | br]
        gemm_mfma<<<dim3(W2 / 128, N_NODES / 128, 1), 256, 0, stream>>>(
            A3, B3T, bl + (size_t)l * HD, br + (size_t)l * HD, HD,
            xlr, N_NODES, W2, 3 * DH, 3 * DH);

        e5_kernel<<<dim3(HD / 256, NT), 256, 0, stream>>>(eemb, We_l, E5);
        gat_online<<<N_NODES, 256, 0, stream>>>(
            xlr, E5, att + (size_t)l * NH * DH, csr, rowptr, cnt, src, attr,
            hist, bgat + (size_t)l * DH, h);
    }

    // out = h @ W_out + b_out   (split-K=4, atomic accumulate)
    split_act8<<<(N_NODES * DH / 8 + 255) / 256, 256, 0, stream>>>(
        h, A3, N_NODES * DH / 8, 5);
    split_w<<<dim3(DH / 32, DH / 32), 256, 0, stream>>>(W_out, B3T, DH, DH);
    init_c<<<2048, 256, 0, stream>>>(out, b_out, N_NODES * DH, 8, nullptr, nullptr);
    gemm_mfma<<<dim3(DH / 128, N_NODES / 128, 4), 256, 0, stream>>>(
        A3, B3T, nullptr, nullptr, DH, out, N_NODES, DH, 3 * DH, 3 * DH / 4);
}